// Round 10
// baseline (459.444 us; speedup 1.0000x reference)
//
#include <hip/hip_runtime.h>
#include <hip/hip_fp16.h>

#define N_NODES 100000
#define N_EDGES 3200000
#define N_GRAPHS 5000
#define BN_EPS 1e-5f
#define HPAD 80        // hidden 75 padded to 80
#define CHUNK 2048     // edges per bucket-sort block
#define NBLKA 1563     // ceil(N_EDGES / CHUNK)
#define NBKT 392       // buckets of 256 nodes (dst >> 8)
#define NPAD2 (NBKT * 256)     // 100352
#define NBLK_TOT (NBKT * NBLKA)  // 612696
#define NS1 2394       // ceil(NBLK_TOT / 256)
#define LALLOC (NS1 * 256)
#define W1S 36         // sW1 row stride: 2-way bank alias only (free)
#define NB_ENC 391     // encode blocks in k_setup
#define NB_GOFF 20     // goff blocks in k_setup
#define NBMLP 782      // k_mlp grid: ceil(N_NODES / 128), 4 nodes/thread
#define PSROW 1568     // pstat row stride (padded)
#define ISC (1.0f / 32767.0f)   // attr dequant scale

// ---------- fused setup: node encoder (+eb fold into mirror) + weight prep + graph offsets ----------
__global__ void __launch_bounds__(256) k_setup(const float* __restrict__ x, const float* __restrict__ nW,
                                               const float* __restrict__ nb, const float* __restrict__ eb,
                                               float* __restrict__ h, __half* __restrict__ h16,
                                               const float* __restrict__ W1, const float* __restrict__ b1,
                                               const float* __restrict__ W2,
                                               float* __restrict__ w1tp, float* __restrict__ b1p,
                                               float* __restrict__ w2p,
                                               const int* __restrict__ batch, int* __restrict__ goff) {
    int bid = blockIdx.x;
    if (bid < NB_ENC) {
        __shared__ float sW[448];
        __shared__ float sb[32];
        __shared__ float seb[32];
        for (int i = threadIdx.x; i < 448; i += 256) sW[i] = nW[i];
        if (threadIdx.x < 32) { sb[threadIdx.x] = nb[threadIdx.x]; seb[threadIdx.x] = eb[threadIdx.x]; }
        __syncthreads();
        int n = bid * 256 + threadIdx.x;
        if (n >= N_NODES) return;
        float xi[14];
#pragma unroll
        for (int k = 0; k < 14; k++) xi[k] = x[n * 14 + k];
        float4* hp = (float4*)(h + (size_t)n * 32);
        __half2* hq = (__half2*)(h16 + (size_t)n * 32);
#pragma unroll
        for (int q = 0; q < 8; q++) {
            float4 acc;
            float* ap = (float*)&acc;
#pragma unroll
            for (int i = 0; i < 4; i++) {
                int c = q * 4 + i;
                float a = sb[c];
#pragma unroll
                for (int k = 0; k < 14; k++) a += xi[k] * sW[k * 32 + c];
                ap[i] = a;
            }
            hp[q] = acc;   // fp32 h WITHOUT eb (self-term)
            int c = q * 4;
            hq[q * 2 + 0] = __floats2half2_rn(acc.x + seb[c + 0], acc.y + seb[c + 1]);
            hq[q * 2 + 1] = __floats2half2_rn(acc.z + seb[c + 2], acc.w + seb[c + 3]);
        }
    } else if (bid == NB_ENC) {
        for (int i = threadIdx.x; i < 2 * HPAD * 32 + 2 * HPAD; i += 256) {
            if (i < 2 * HPAD * 32) {
                int l = i / (HPAD * 32), r = i % (HPAD * 32);
                int j = r / 32, c = r % 32;
                w1tp[i] = (j < 75) ? W1[l * 2400 + c * 75 + j] : 0.f;
                w2p[i]  = (j < 75) ? W2[l * 2400 + j * 32 + c] : 0.f;
            } else {
                int k = i - 2 * HPAD * 32;
                int l = k / HPAD, j = k % HPAD;
                b1p[k] = (j < 75) ? b1[l * 75 + j] : 0.f;
            }
        }
    } else {
        int g = (bid - NB_ENC - 1) * 256 + threadIdx.x;
        if (g > N_GRAPHS) return;
        int lo = 0, hi = N_NODES;
        while (lo < hi) {
            int mid = (lo + hi) >> 1;
            if (batch[mid] < g) lo = mid + 1; else hi = mid;
        }
        goff[g] = lo;
    }
}

// ---------- bucket sort phase A: per-chunk histogram (LDS atomics only) ----------
__global__ void __launch_bounds__(256) ksA(const int* __restrict__ ei, int* __restrict__ cmat) {
    __shared__ int lh[NBKT];
    for (int i = threadIdx.x; i < NBKT; i += 256) lh[i] = 0;
    __syncthreads();
    int b0 = blockIdx.x * CHUNK;
    for (int i = threadIdx.x; i < CHUNK; i += 256) {
        int e = b0 + i;
        if (e < N_EDGES) atomicAdd(&lh[ei[N_EDGES + e] >> 8], 1);
    }
    __syncthreads();
    for (int i = threadIdx.x; i < NBKT; i += 256)
        cmat[i * NBLKA + blockIdx.x] = lh[i];
}

// ---------- 3-kernel exclusive scan of cmat ----------
__global__ void ks1(const int* __restrict__ a, int* __restrict__ bs) {
    __shared__ int s[256];
    int i = blockIdx.x * 256 + threadIdx.x;
    s[threadIdx.x] = a[i];
    __syncthreads();
    for (int o = 128; o > 0; o >>= 1) {
        if (threadIdx.x < o) s[threadIdx.x] += s[threadIdx.x + o];
        __syncthreads();
    }
    if (threadIdx.x == 0) bs[blockIdx.x] = s[0];
}

template<int NSX, int VPTX>
__global__ void ks2(int* __restrict__ bs) {
    __shared__ int s[256];
    int t = threadIdx.x;
    int v[VPTX];
    int base = t * VPTX, sum = 0;
#pragma unroll
    for (int k = 0; k < VPTX; k++) {
        int idx = base + k;
        int x = (idx < NSX) ? bs[idx] : 0;
        v[k] = sum; sum += x;
    }
    s[t] = sum;
    __syncthreads();
    for (int o = 1; o < 256; o <<= 1) {
        int add = (t >= o) ? s[t - o] : 0;
        __syncthreads();
        s[t] += add;
        __syncthreads();
    }
    int excl = (t == 0) ? 0 : s[t - 1];
#pragma unroll
    for (int k = 0; k < VPTX; k++) {
        int idx = base + k;
        if (idx < NSX) bs[idx] = excl + v[k];
    }
}

__global__ void ks3(int* __restrict__ a, const int* __restrict__ bs) {
    __shared__ int s[256];
    int t = threadIdx.x, i = blockIdx.x * 256 + t;
    int v = a[i];
    s[t] = v;
    __syncthreads();
    for (int o = 1; o < 256; o <<= 1) {
        int add = (t >= o) ? s[t - o] : 0;
        __syncthreads();
        s[t] += add;
        __syncthreads();
    }
    a[i] = s[t] - v + bs[blockIdx.x];
}

// ---------- phase B: counting sort in LDS, 8-byte quantized records + key/dl bytes ----------
__global__ void __launch_bounds__(256) ksB(const int* __restrict__ ei, const float* __restrict__ ea,
                                           const int* __restrict__ cmat, uint2* __restrict__ buf1,
                                           unsigned char* __restrict__ key) {
    __shared__ uint2 rec[CHUNK];           // 16 KB
    __shared__ unsigned short sbkt[CHUNK]; // 4 KB
    __shared__ unsigned char sdl[CHUNK];   // 2 KB
    __shared__ int lh[NBKT];
    __shared__ int lex[NBKT];
    __shared__ int gb[NBKT];
    __shared__ int sc[256];
    int t = threadIdx.x;
    int b0 = blockIdx.x * CHUNK;
    int nval = min(CHUNK, N_EDGES - b0);
    for (int i = t; i < NBKT; i += 256) lh[i] = 0;
    __syncthreads();
    for (int i = t; i < nval; i += 256)
        atomicAdd(&lh[ei[N_EDGES + b0 + i] >> 8], 1);
    __syncthreads();
    int x0 = (t * 2 < NBKT) ? lh[t * 2] : 0;
    int x1 = (t * 2 + 1 < NBKT) ? lh[t * 2 + 1] : 0;
    int v0 = 0, v1 = x0, run = x0 + x1;
    sc[t] = run;
    __syncthreads();
    for (int o = 1; o < 256; o <<= 1) {
        int add = (t >= o) ? sc[t - o] : 0;
        __syncthreads();
        sc[t] += add;
        __syncthreads();
    }
    int excl = (t == 0) ? 0 : sc[t - 1];
    if (t * 2 < NBKT) {
        int base = excl + v0;
        lex[t * 2] = base; lh[t * 2] = base;
        gb[t * 2] = cmat[(t * 2) * NBLKA + blockIdx.x];
    }
    if (t * 2 + 1 < NBKT) {
        int base = excl + v1;
        lex[t * 2 + 1] = base; lh[t * 2 + 1] = base;
        gb[t * 2 + 1] = cmat[(t * 2 + 1) * NBLKA + blockIdx.x];
    }
    __syncthreads();
    for (int i = t; i < nval; i += 256) {
        int e = b0 + i;
        int src = ei[e], dst = ei[N_EDGES + e];
        float a0 = ea[(size_t)e * 3 + 0], a1 = ea[(size_t)e * 3 + 1], a2 = ea[(size_t)e * 3 + 2];
        unsigned q0 = (unsigned)(int)(a0 * 32767.f + 0.5f);
        unsigned q1 = (unsigned)(int)(a1 * 32767.f + 0.5f);
        unsigned q2 = (unsigned)(int)(a2 * 32767.f + 0.5f);
        int bkt = dst >> 8;
        int r = atomicAdd(&lh[bkt], 1);
        rec[r] = make_uint2((unsigned)src | (q0 << 17), q1 | (q2 << 15));
        sbkt[r] = (unsigned short)bkt;
        sdl[r] = (unsigned char)(dst & 255);
    }
    __syncthreads();
    for (int p = t; p < nval; p += 256) {
        int bkt = sbkt[p];
        int gp = gb[bkt] + (p - lex[bkt]);
        buf1[gp] = rec[p];
        key[gp] = sdl[p];
    }
}

// ---------- phase C: per-256-node-bucket exact CSR; decode 8B records -> float4 packed ----------
__global__ void __launch_bounds__(512) ksC(const int* __restrict__ cmat, const uint2* __restrict__ buf1,
                                           const unsigned char* __restrict__ key,
                                           float4* __restrict__ packed, int* __restrict__ offs) {
    __shared__ int cnt[256];
    __shared__ int sc2[256];
    __shared__ int excl[256];
    int g = blockIdx.x, t = threadIdx.x;
    int bb = cmat[g * NBLKA];
    int be = (g == NBKT - 1) ? N_EDGES : cmat[(g + 1) * NBLKA];
    if (t < 256) cnt[t] = 0;
    __syncthreads();
    for (int j = bb + t; j < be; j += 512) atomicAdd(&cnt[key[j]], 1);
    __syncthreads();
    if (t < 256) sc2[t] = cnt[t];
    __syncthreads();
    for (int o = 1; o < 256; o <<= 1) {
        int add = 0;
        if (t < 256 && t >= o) add = sc2[t - o];
        __syncthreads();
        if (t < 256) sc2[t] += add;
        __syncthreads();
    }
    if (t < 256) {
        excl[t] = sc2[t] - cnt[t];
        offs[(g << 8) + t] = bb + excl[t];
        cnt[t] = 0;
    }
    if (g == NBKT - 1 && t == 0) offs[NPAD2] = N_EDGES;
    __syncthreads();
    for (int j = bb + t; j < be; j += 512) {
        uint2 r = buf1[j];
        int dl = key[j];
        int rank = atomicAdd(&cnt[dl], 1);
        unsigned src = r.x & 0x1FFFFu;
        float a0 = (float)(r.x >> 17) * ISC;
        float a1 = (float)(r.y & 0x7FFFu) * ISC;
        float a2 = (float)(r.y >> 15) * ISC;
        packed[bb + excl[dl] + rank] = make_float4(a0, a1, a2, __int_as_float((int)(src << 5)));
    }
}

// ---------- pull aggregation: 32 threads/node, fp16 gather, unroll-4 (4 indep load chains) ----------
// packed.w = src<<5 (h16 element offset); BN=true applies relu(BN1(z)) to self-term inline
template<bool BN>
__global__ void __launch_bounds__(256) k_agg(const float4* __restrict__ packed,
                                             const int* __restrict__ offs,
                                             const float* __restrict__ eW,
                                             const __half* __restrict__ h16,
                                             const float* __restrict__ hs,
                                             const float* __restrict__ stats,
                                             const float* __restrict__ bng, const float* __restrict__ bnb,
                                             float* __restrict__ zin) {
    int t = blockIdx.x * 256 + threadIdx.x;   // N_NODES*32 exact
    int n = t >> 5, s = t & 31;
    int q = s & 7, part = s >> 3;
    int c0 = q * 4;
    float w0[4], w1[4], w2[4];
#pragma unroll
    for (int i = 0; i < 4; i++) {
        w0[i] = eW[c0 + i];
        w1[i] = eW[32 + c0 + i];
        w2[i] = eW[64 + c0 + i];
    }
    int beg = offs[n], end = offs[n + 1];
    float acc0[4] = {0.f, 0.f, 0.f, 0.f};
    float acc1[4] = {0.f, 0.f, 0.f, 0.f};
    int j = beg + part;
    for (; j + 12 < end; j += 16) {
        float4 pa = packed[j];
        float4 pb = packed[j + 4];
        float4 pc = packed[j + 8];
        float4 pd = packed[j + 12];
        unsigned offa = (unsigned)__float_as_int(pa.w) + (unsigned)c0;
        unsigned offb = (unsigned)__float_as_int(pb.w) + (unsigned)c0;
        unsigned offc = (unsigned)__float_as_int(pc.w) + (unsigned)c0;
        unsigned offd = (unsigned)__float_as_int(pd.w) + (unsigned)c0;
        float2 ra = *(const float2*)(h16 + offa);
        float2 rb = *(const float2*)(h16 + offb);
        float2 rc = *(const float2*)(h16 + offc);
        float2 rd = *(const float2*)(h16 + offd);
        float2 a01 = __half22float2(*(__half2*)&ra.x);
        float2 a23 = __half22float2(*(__half2*)&ra.y);
        float2 b01 = __half22float2(*(__half2*)&rb.x);
        float2 b23 = __half22float2(*(__half2*)&rb.y);
        float2 c01 = __half22float2(*(__half2*)&rc.x);
        float2 c23 = __half22float2(*(__half2*)&rc.y);
        float2 d01 = __half22float2(*(__half2*)&rd.x);
        float2 d23 = __half22float2(*(__half2*)&rd.y);
        float ha4[4] = {a01.x, a01.y, a23.x, a23.y};
        float hb4[4] = {b01.x, b01.y, b23.x, b23.y};
        float hc4[4] = {c01.x, c01.y, c23.x, c23.y};
        float hd4[4] = {d01.x, d01.y, d23.x, d23.y};
#pragma unroll
        for (int i = 0; i < 4; i++) {
            acc0[i] += fmaxf(ha4[i] + pa.x * w0[i] + pa.y * w1[i] + pa.z * w2[i], 0.f);
            acc1[i] += fmaxf(hb4[i] + pb.x * w0[i] + pb.y * w1[i] + pb.z * w2[i], 0.f);
            acc0[i] += fmaxf(hc4[i] + pc.x * w0[i] + pc.y * w1[i] + pc.z * w2[i], 0.f);
            acc1[i] += fmaxf(hd4[i] + pd.x * w0[i] + pd.y * w1[i] + pd.z * w2[i], 0.f);
        }
    }
    for (; j < end; j += 4) {
        float4 p = packed[j];
        unsigned offp = (unsigned)__float_as_int(p.w) + (unsigned)c0;
        float2 r = *(const float2*)(h16 + offp);
        float2 a01 = __half22float2(*(__half2*)&r.x);
        float2 a23 = __half22float2(*(__half2*)&r.y);
        float hp4[4] = {a01.x, a01.y, a23.x, a23.y};
#pragma unroll
        for (int i = 0; i < 4; i++)
            acc0[i] += fmaxf(hp4[i] + p.x * w0[i] + p.y * w1[i] + p.z * w2[i], 0.f);
    }
    float acc[4];
#pragma unroll
    for (int i = 0; i < 4; i++) {
        acc[i] = acc0[i] + acc1[i];
        acc[i] += __shfl_xor(acc[i], 8, 64);
        acc[i] += __shfl_xor(acc[i], 16, 64);
    }
    if (part == 0) {
        float4 hq = *(const float4*)(hs + (size_t)n * 32 + c0);   // coalesced, L2-warm
        float* hp = (float*)&hq;
        float sv[4];
        if (BN) {
            const float invN = 1.0f / (float)N_NODES;
#pragma unroll
            for (int i = 0; i < 4; i++) {
                int c = c0 + i;
                float mu = stats[c] * invN;
                float var = stats[32 + c] * invN - mu * mu;
                float scl = bng[c] / sqrtf(var + BN_EPS);
                float sft = bnb[c] - mu * scl;
                sv[i] = fmaxf(hp[i] * scl + sft, 0.f);
            }
        } else {
#pragma unroll
            for (int i = 0; i < 4; i++) sv[i] = hp[i];
        }
        *(float4*)(zin + (size_t)n * 32 + c0) =
            make_float4(acc[0] + sv[0], acc[1] + sv[1], acc[2] + sv[2], acc[3] + sv[3]);
    }
}

// ---------- fused MLP, 4 nodes/thread, named float4 regs + per-block BN partial stats ----------
// psum/psq aliased onto hidL (after a barrier) to stay <= 64 KiB LDS
__global__ void __launch_bounds__(256, 2) k_mlp(float* __restrict__ zio,
                                                const float* __restrict__ W1, const float* __restrict__ B1,
                                                const float* __restrict__ W2, const float* __restrict__ b2,
                                                float* __restrict__ pstat) {
    __shared__ float sW1[HPAD * W1S];  // 11.25 KB
    __shared__ float sW2[2560];        // 10 KB
    __shared__ float sB1[80];
    __shared__ float sb2[32];
    __shared__ float hidL[128 * 84];   // 42 KB (128 nodes/block); first 256 floats reused for stats
    for (int i = threadIdx.x; i < 2560; i += 256) {
        int j = i >> 5, c = i & 31;
        sW1[j * W1S + c] = W1[i];
        sW2[i] = W2[i];
    }
    if (threadIdx.x < 80) sB1[threadIdx.x] = B1[threadIdx.x];
    if (threadIdx.x < 32) sb2[threadIdx.x] = b2[threadIdx.x];
    __syncthreads();
    unsigned lane = threadIdx.x & 63;
    unsigned wv = threadIdx.x >> 6;
    unsigned oct = lane >> 3;
    unsigned nd = lane & 7;
    unsigned nA = blockIdx.x * 128 + wv * 32 + nd;   // wave covers 32 consecutive nodes
    unsigned nB = nA + 8, nC = nA + 16, nD = nA + 24;
    bool vA = nA < N_NODES, vB = nB < N_NODES, vC = nC < N_NODES, vD = nD < N_NODES;
    const float4* apA = (const float4*)(zio + (size_t)(vA ? nA : (N_NODES - 1)) * 32);
    const float4* apB = (const float4*)(zio + (size_t)(vB ? nB : (N_NODES - 1)) * 32);
    const float4* apC = (const float4*)(zio + (size_t)(vC ? nC : (N_NODES - 1)) * 32);
    const float4* apD = (const float4*)(zio + (size_t)(vD ? nD : (N_NODES - 1)) * 32);
    // 32 NAMED float4 registers — no spillable aggregates
    float4 zA0 = apA[0], zA1 = apA[1], zA2 = apA[2], zA3 = apA[3];
    float4 zA4 = apA[4], zA5 = apA[5], zA6 = apA[6], zA7 = apA[7];
    float4 zB0 = apB[0], zB1 = apB[1], zB2 = apB[2], zB3 = apB[3];
    float4 zB4 = apB[4], zB5 = apB[5], zB6 = apB[6], zB7 = apB[7];
    float4 zC0 = apC[0], zC1 = apC[1], zC2 = apC[2], zC3 = apC[3];
    float4 zC4 = apC[4], zC5 = apC[5], zC6 = apC[6], zC7 = apC[7];
    float4 zD0 = apD[0], zD1 = apD[1], zD2 = apD[2], zD3 = apD[3];
    float4 zD4 = apD[4], zD5 = apD[5], zD6 = apD[6], zD7 = apD[7];
    float* hrowA = &hidL[(wv * 32 + nd) * 84];
    float* hrowB = &hidL[(wv * 32 + 8 + nd) * 84];
    float* hrowC = &hidL[(wv * 32 + 16 + nd) * 84];
    float* hrowD = &hidL[(wv * 32 + 24 + nd) * 84];
#pragma unroll
    for (int i = 0; i < 10; i++) {
        int j = (int)oct * 10 + i;
        const float4* wp = (const float4*)(sW1 + j * W1S);
        float a0 = 0.f, a1 = 0.f, a2 = 0.f, a3 = 0.f;
        float b0 = 0.f, b1v = 0.f, b2v = 0.f, b3 = 0.f;
        float c0v = 0.f, c1v = 0.f, c2v = 0.f, c3v = 0.f;
        float d0 = 0.f, d1 = 0.f, d2 = 0.f, d3 = 0.f;
#define MLP_STEP(Q, ZA, ZB, ZC, ZD)                           \
        { float4 w4 = wp[Q];                                  \
          a0 += ZA.x * w4.x; a1 += ZA.y * w4.y;               \
          a2 += ZA.z * w4.z; a3 += ZA.w * w4.w;               \
          b0 += ZB.x * w4.x; b1v += ZB.y * w4.y;              \
          b2v += ZB.z * w4.z; b3 += ZB.w * w4.w;              \
          c0v += ZC.x * w4.x; c1v += ZC.y * w4.y;             \
          c2v += ZC.z * w4.z; c3v += ZC.w * w4.w;             \
          d0 += ZD.x * w4.x; d1 += ZD.y * w4.y;               \
          d2 += ZD.z * w4.z; d3 += ZD.w * w4.w; }
        MLP_STEP(0, zA0, zB0, zC0, zD0)
        MLP_STEP(1, zA1, zB1, zC1, zD1)
        MLP_STEP(2, zA2, zB2, zC2, zD2)
        MLP_STEP(3, zA3, zB3, zC3, zD3)
        MLP_STEP(4, zA4, zB4, zC4, zD4)
        MLP_STEP(5, zA5, zB5, zC5, zD5)
        MLP_STEP(6, zA6, zB6, zC6, zD6)
        MLP_STEP(7, zA7, zB7, zC7, zD7)
#undef MLP_STEP
        float bias = sB1[j];
        hrowA[oct * 10 + i] = fmaxf(bias + ((a0 + a1) + (a2 + a3)), 0.f);
        hrowB[oct * 10 + i] = fmaxf(bias + ((b0 + b1v) + (b2v + b3)), 0.f);
        hrowC[oct * 10 + i] = fmaxf(bias + ((c0v + c1v) + (c2v + c3v)), 0.f);
        hrowD[oct * 10 + i] = fmaxf(bias + ((d0 + d1) + (d2 + d3)), 0.f);
    }
    // wave-synchronous: hidL rows for this wave's 32 nodes written/read by same wave
    float4 zoA = *(const float4*)(sb2 + oct * 4);
    float4 zoB = zoA, zoC = zoA, zoD = zoA;
    const float4* hvA4 = (const float4*)hrowA;
    const float4* hvB4 = (const float4*)hrowB;
    const float4* hvC4 = (const float4*)hrowC;
    const float4* hvD4 = (const float4*)hrowD;
#pragma unroll
    for (int k = 0; k < 20; k++) {
        float4 ha = hvA4[k];
        float4 hb = hvB4[k];
        float4 hc = hvC4[k];
        float4 hd = hvD4[k];
        const float* wr = sW2 + (k * 4) * 32 + oct * 4;
        float4 wa = *(const float4*)(wr);
        float4 wb = *(const float4*)(wr + 32);
        float4 wc = *(const float4*)(wr + 64);
        float4 wd = *(const float4*)(wr + 96);
        zoA.x += ha.x * wa.x + ha.y * wb.x + ha.z * wc.x + ha.w * wd.x;
        zoA.y += ha.x * wa.y + ha.y * wb.y + ha.z * wc.y + ha.w * wd.y;
        zoA.z += ha.x * wa.z + ha.y * wb.z + ha.z * wc.z + ha.w * wd.z;
        zoA.w += ha.x * wa.w + ha.y * wb.w + ha.z * wc.w + ha.w * wd.w;
        zoB.x += hb.x * wa.x + hb.y * wb.x + hb.z * wc.x + hb.w * wd.x;
        zoB.y += hb.x * wa.y + hb.y * wb.y + hb.z * wc.y + hb.w * wd.y;
        zoB.z += hb.x * wa.z + hb.y * wb.z + hb.z * wc.z + hb.w * wd.z;
        zoB.w += hb.x * wa.w + hb.y * wb.w + hb.z * wc.w + hb.w * wd.w;
        zoC.x += hc.x * wa.x + hc.y * wb.x + hc.z * wc.x + hc.w * wd.x;
        zoC.y += hc.x * wa.y + hc.y * wb.y + hc.z * wc.y + hc.w * wd.y;
        zoC.z += hc.x * wa.z + hc.y * wb.z + hc.z * wc.z + hc.w * wd.z;
        zoC.w += hc.x * wa.w + hc.y * wb.w + hc.z * wc.w + hc.w * wd.w;
        zoD.x += hd.x * wa.x + hd.y * wb.x + hd.z * wc.x + hd.w * wd.x;
        zoD.y += hd.x * wa.y + hd.y * wb.y + hd.z * wc.y + hd.w * wd.y;
        zoD.z += hd.x * wa.z + hd.y * wb.z + hd.z * wc.z + hd.w * wd.z;
        zoD.w += hd.x * wa.w + hd.y * wb.w + hd.z * wc.w + hd.w * wd.w;
    }
    if (vA) *(float4*)(zio + (size_t)nA * 32 + oct * 4) = zoA;
    if (vB) *(float4*)(zio + (size_t)nB * 32 + oct * 4) = zoB;
    if (vC) *(float4*)(zio + (size_t)nC * 32 + oct * 4) = zoC;
    if (vD) *(float4*)(zio + (size_t)nD * 32 + oct * 4) = zoD;
    // ---- per-block BN partial stats (plain stores, no atomics) ----
    float s0 = (vA ? zoA.x : 0.f) + (vB ? zoB.x : 0.f) + (vC ? zoC.x : 0.f) + (vD ? zoD.x : 0.f);
    float s1 = (vA ? zoA.y : 0.f) + (vB ? zoB.y : 0.f) + (vC ? zoC.y : 0.f) + (vD ? zoD.y : 0.f);
    float s2 = (vA ? zoA.z : 0.f) + (vB ? zoB.z : 0.f) + (vC ? zoC.z : 0.f) + (vD ? zoD.z : 0.f);
    float s3 = (vA ? zoA.w : 0.f) + (vB ? zoB.w : 0.f) + (vC ? zoC.w : 0.f) + (vD ? zoD.w : 0.f);
    float q0 = (vA ? zoA.x * zoA.x : 0.f) + (vB ? zoB.x * zoB.x : 0.f) + (vC ? zoC.x * zoC.x : 0.f) + (vD ? zoD.x * zoD.x : 0.f);
    float q1 = (vA ? zoA.y * zoA.y : 0.f) + (vB ? zoB.y * zoB.y : 0.f) + (vC ? zoC.y * zoC.y : 0.f) + (vD ? zoD.y * zoD.y : 0.f);
    float q2 = (vA ? zoA.z * zoA.z : 0.f) + (vB ? zoB.z * zoB.z : 0.f) + (vC ? zoC.z * zoC.z : 0.f) + (vD ? zoD.z * zoD.z : 0.f);
    float q3 = (vA ? zoA.w * zoA.w : 0.f) + (vB ? zoB.w * zoB.w : 0.f) + (vC ? zoC.w * zoC.w : 0.f) + (vD ? zoD.w * zoD.w : 0.f);
#pragma unroll
    for (int m = 1; m < 8; m <<= 1) {
        s0 += __shfl_xor(s0, m, 64); s1 += __shfl_xor(s1, m, 64);
        s2 += __shfl_xor(s2, m, 64); s3 += __shfl_xor(s3, m, 64);
        q0 += __shfl_xor(q0, m, 64); q1 += __shfl_xor(q1, m, 64);
        q2 += __shfl_xor(q2, m, 64); q3 += __shfl_xor(q3, m, 64);
    }
    __syncthreads();            // all hidL reads complete before aliasing as stats scratch
    float* psum = hidL;         // [4][32]
    float* psq  = hidL + 128;   // [4][32]
    if (nd == 0) {
        int base = (int)wv * 32 + (int)oct * 4;
        psum[base + 0] = s0; psum[base + 1] = s1; psum[base + 2] = s2; psum[base + 3] = s3;
        psq[base + 0] = q0;  psq[base + 1] = q1;  psq[base + 2] = q2;  psq[base + 3] = q3;
    }
    __syncthreads();
    if (threadIdx.x < 32) {
        int c = threadIdx.x;
        pstat[(size_t)c * PSROW + blockIdx.x] =
            psum[c] + psum[32 + c] + psum[64 + c] + psum[96 + c];
    } else if (threadIdx.x < 64) {
        int c = threadIdx.x - 32;
        pstat[(size_t)(32 + c) * PSROW + blockIdx.x] =
            psq[c] + psq[32 + c] + psq[64 + c] + psq[96 + c];
    }
}

// ---------- stats reducer: 64 blocks, coalesced row sums ----------
__global__ void __launch_bounds__(256) k_statsR(const float* __restrict__ pstat, float* __restrict__ stats) {
    __shared__ float ls[4];
    int r = blockIdx.x;
    const float* row = pstat + (size_t)r * PSROW;
    float s = 0.f;
    for (int i = threadIdx.x; i < NBMLP; i += 256) s += row[i];
#pragma unroll
    for (int m = 1; m < 64; m <<= 1) s += __shfl_xor(s, m, 64);
    if ((threadIdx.x & 63) == 0) ls[threadIdx.x >> 6] = s;
    __syncthreads();
    if (threadIdx.x == 0) stats[r] = ls[0] + ls[1] + ls[2] + ls[3];
}

// ---------- BN apply + relu + eb fold, fp16 mirror only (layer-1) ----------
__global__ void k_bnh(const float* __restrict__ z, __half* __restrict__ m,
                      const float* __restrict__ stats, const float* __restrict__ g,
                      const float* __restrict__ b, const float* __restrict__ eb) {
    int t = blockIdx.x * 256 + threadIdx.x;
    if (t >= N_NODES * 8) return;
    int q = t & 7;
    float4 zv = ((const float4*)z)[t];
    float* zp = (float*)&zv;
    float ov[4];
    const float invN = 1.0f / (float)N_NODES;
#pragma unroll
    for (int i = 0; i < 4; i++) {
        int c = q * 4 + i;
        float mu = stats[c] * invN;
        float var = stats[32 + c] * invN - mu * mu;
        float sc = g[c] / sqrtf(var + BN_EPS);
        ov[i] = fmaxf((zp[i] - mu) * sc + b[c], 0.f) + eb[c];
    }
    __half2* hq = (__half2*)(m + (size_t)t * 4);
    hq[0] = __floats2half2_rn(ov[0], ov[1]);
    hq[1] = __floats2half2_rn(ov[2], ov[3]);
}

// ---------- fused mean-pool (BN2+relu inline) + head MLP: one wave per graph ----------
__global__ void __launch_bounds__(256) k_poolhead(const float* __restrict__ z, const int* __restrict__ goff,
                                                  const float* __restrict__ stats,
                                                  const float* __restrict__ bg, const float* __restrict__ bb,
                                                  const float* __restrict__ W1, const float* __restrict__ b1,
                                                  const float* __restrict__ W2, const float* __restrict__ b2,
                                                  float* __restrict__ out) {
    __shared__ float sW1[512];
    __shared__ float sb1[16], sW2[32], sb2[2];
    __shared__ float gxs[4][32];
    for (int i = threadIdx.x; i < 512; i += 256) sW1[i] = W1[i];
    if (threadIdx.x < 16) sb1[threadIdx.x] = b1[threadIdx.x];
    if (threadIdx.x < 32) sW2[threadIdx.x] = W2[threadIdx.x];
    if (threadIdx.x < 2) sb2[threadIdx.x] = b2[threadIdx.x];
    __syncthreads();
    int wid = threadIdx.x >> 6, lane = threadIdx.x & 63;
    int gi = blockIdx.x * 4 + wid;
    int s = goff[gi], e = goff[gi + 1];
    int c = lane & 31, half = lane >> 5;
    const float invN = 1.0f / (float)N_NODES;
    float mu = stats[c] * invN;
    float var = stats[32 + c] * invN - mu * mu;
    float scl = bg[c] / sqrtf(var + BN_EPS);
    float sft = bb[c] - mu * scl;
    float acc = 0.f;
    for (int n = s + half; n < e; n += 2)
        acc += fmaxf(z[(size_t)n * 32 + c] * scl + sft, 0.f);
    acc += __shfl_down(acc, 32, 64);
    float inv = 1.0f / fmaxf((float)(e - s), 1.0f);
    if (lane < 32) gxs[wid][c] = acc * inv;
    float hid = 0.f;
    if (lane < 16) {
        float a = sb1[lane];
#pragma unroll
        for (int cc = 0; cc < 32; cc++) a += gxs[wid][cc] * sW1[cc * 16 + lane];
        hid = fmaxf(a, 0.f);
    }
    float p0 = 0.f, p1 = 0.f;
    if (lane < 16) { p0 = hid * sW2[lane * 2 + 0]; p1 = hid * sW2[lane * 2 + 1]; }
#pragma unroll
    for (int m = 1; m < 16; m <<= 1) {
        p0 += __shfl_xor(p0, m, 64);
        p1 += __shfl_xor(p1, m, 64);
    }
    if (lane == 0) {
        out[(size_t)gi * 2 + 0] = p0 + sb2[0];
        out[(size_t)gi * 2 + 1] = p1 + sb2[1];
    }
}

extern "C" void kernel_launch(void* const* d_in, const int* in_sizes, int n_in,
                              void* d_out, int out_size, void* d_ws, size_t ws_size,
                              hipStream_t stream) {
    const float* x       = (const float*)d_in[0];
    const int*   ei      = (const int*)d_in[1];
    const float* eattr   = (const float*)d_in[2];
    const int*   batch   = (const int*)d_in[3];
    const float* node_w  = (const float*)d_in[4];
    const float* node_b  = (const float*)d_in[5];
    const float* edge_w  = (const float*)d_in[6];
    const float* edge_b  = (const float*)d_in[7];
    const float* conv_w1 = (const float*)d_in[8];
    const float* conv_b1 = (const float*)d_in[9];
    const float* conv_w2 = (const float*)d_in[10];
    const float* conv_b2 = (const float*)d_in[11];
    const float* bn_g    = (const float*)d_in[12];
    const float* bn_b    = (const float*)d_in[13];
    const float* lin1_w  = (const float*)d_in[14];
    const float* lin1_b  = (const float*)d_in[15];
    const float* lin2_w  = (const float*)d_in[16];
    const float* lin2_b  = (const float*)d_in[17];
    float* out = (float*)d_out;

    uint2*  buf1    = (uint2*)d_ws;                         // 25.6 MB (8-B quantized records)
    float4* packed  = (float4*)(buf1 + N_EDGES);            // 51.2 MB
    float*  h       = (float*)(packed + N_EDGES);           // 12.8 MB (h0, then zin2/z2)
    float*  agg     = h + (size_t)N_NODES * 32;             // 12.8 MB (zin1/z1)
    __half* m16     = (__half*)(agg + (size_t)N_NODES * 32);// 6.4 MB (h0+eb mirror, then BN1+eb mirror)
    unsigned char* key = (unsigned char*)(m16 + (size_t)N_NODES * 32); // 3.2 MB
    int*    cmat    = (int*)(key + N_EDGES);                // LALLOC ints
    float*  stats   = (float*)(cmat + LALLOC);              // 128 floats
    int*    t1      = (int*)(stats + 128);                  // 2560
    int*    offs    = t1 + 2560;                            // NPAD2+1
    int*    goff    = offs + NPAD2 + 1;                     // N_GRAPHS+1
    float*  pstat   = (float*)(goff + N_GRAPHS + 1);        // 64*PSROW
    float*  w1tp    = pstat + 64 * PSROW;                   // 2*80*32
    float*  b1p     = w1tp + 2 * HPAD * 32;                 // 2*80
    float*  w2p     = b1p + 2 * HPAD;                       // 2*80*32

    int nb_vec = (N_NODES * 8 + 255) / 256;

    hipMemsetAsync(cmat + NBLK_TOT, 0, (size_t)(LALLOC - NBLK_TOT + 128) * sizeof(int), stream);
    k_setup<<<NB_ENC + 1 + NB_GOFF, 256, 0, stream>>>(x, node_w, node_b, edge_b, h, m16,
                                                      conv_w1, conv_b1, conv_w2, w1tp, b1p, w2p,
                                                      batch, goff);

    ksA<<<NBLKA, 256, 0, stream>>>(ei, cmat);
    ks1<<<NS1, 256, 0, stream>>>(cmat, t1);
    ks2<NS1, 10><<<1, 256, 0, stream>>>(t1);
    ks3<<<NS1, 256, 0, stream>>>(cmat, t1);
    ksB<<<NBLKA, 256, 0, stream>>>(ei, eattr, cmat, buf1, key);
    ksC<<<NBKT, 512, 0, stream>>>(cmat, buf1, key, packed, offs);

    // layer 1
    k_agg<false><<<N_NODES * 32 / 256, 256, 0, stream>>>(packed, offs, edge_w,
                                                         m16, h, stats, bn_g, bn_b, agg);
    k_mlp<<<NBMLP, 256, 0, stream>>>(agg, w1tp, b1p, w2p, conv_b2, pstat);
    k_statsR<<<64, 256, 0, stream>>>(pstat, stats);
    k_bnh<<<nb_vec, 256, 0, stream>>>(agg, m16, stats, bn_g, bn_b, edge_b);
    // layer 2
    k_agg<true><<<N_NODES * 32 / 256, 256, 0, stream>>>(packed, offs, edge_w,
                                                        m16, agg, stats, bn_g, bn_b, h);
    k_mlp<<<NBMLP, 256, 0, stream>>>(h, w1tp + HPAD * 32, b1p + HPAD,
                                     w2p + HPAD * 32, conv_b2 + 32, pstat);
    k_statsR<<<64, 256, 0, stream>>>(pstat, stats + 64);
    k_poolhead<<<N_GRAPHS / 4, 256, 0, stream>>>(h, goff, stats + 64, bn_g + 32, bn_b + 32,
                                                 lin1_w, lin1_b, lin2_w, lin2_b, out);
}

// Round 11
// 434.509 us; speedup vs baseline: 1.0574x; 1.0574x over previous
//
#include <hip/hip_runtime.h>
#include <hip/hip_fp16.h>

#define N_NODES 100000
#define N_EDGES 3200000
#define N_GRAPHS 5000
#define BN_EPS 1e-5f
#define HPAD 80        // hidden 75 padded to 80
#define CHUNK 2048     // edges per bucket-sort block
#define NBLKA 1563     // ceil(N_EDGES / CHUNK)
#define NBKT 392       // buckets of 256 nodes (dst >> 8)
#define NPAD2 (NBKT * 256)     // 100352
#define NBLK_TOT (NBKT * NBLKA)  // 612696
#define NS1 2394       // ceil(NBLK_TOT / 256)
#define LALLOC (NS1 * 256)
#define W1S 36         // sW1 row stride: 2-way bank alias only (free)
#define NB_ENC 391     // encode blocks in k_setup
#define NB_GOFF 20     // goff blocks in k_setup
#define NBMLP 1563     // k_mlp grid: 2 nodes/thread, 64 nodes/block
#define PSROW 1568     // pstat row stride (padded)
#define ISC (1.0f / 32767.0f)   // attr dequant scale

// ---------- fused setup: node encoder (+eb fold into mirror) + weight prep + graph offsets ----------
__global__ void __launch_bounds__(256) k_setup(const float* __restrict__ x, const float* __restrict__ nW,
                                               const float* __restrict__ nb, const float* __restrict__ eb,
                                               float* __restrict__ h, __half* __restrict__ h16,
                                               const float* __restrict__ W1, const float* __restrict__ b1,
                                               const float* __restrict__ W2,
                                               float* __restrict__ w1tp, float* __restrict__ b1p,
                                               float* __restrict__ w2p,
                                               const int* __restrict__ batch, int* __restrict__ goff) {
    int bid = blockIdx.x;
    if (bid < NB_ENC) {
        __shared__ float sW[448];
        __shared__ float sb[32];
        __shared__ float seb[32];
        for (int i = threadIdx.x; i < 448; i += 256) sW[i] = nW[i];
        if (threadIdx.x < 32) { sb[threadIdx.x] = nb[threadIdx.x]; seb[threadIdx.x] = eb[threadIdx.x]; }
        __syncthreads();
        int n = bid * 256 + threadIdx.x;
        if (n >= N_NODES) return;
        float xi[14];
#pragma unroll
        for (int k = 0; k < 14; k++) xi[k] = x[n * 14 + k];
        float4* hp = (float4*)(h + (size_t)n * 32);
        __half2* hq = (__half2*)(h16 + (size_t)n * 32);
#pragma unroll
        for (int q = 0; q < 8; q++) {
            float4 acc;
            float* ap = (float*)&acc;
#pragma unroll
            for (int i = 0; i < 4; i++) {
                int c = q * 4 + i;
                float a = sb[c];
#pragma unroll
                for (int k = 0; k < 14; k++) a += xi[k] * sW[k * 32 + c];
                ap[i] = a;
            }
            hp[q] = acc;   // fp32 h WITHOUT eb (self-term)
            int c = q * 4;
            hq[q * 2 + 0] = __floats2half2_rn(acc.x + seb[c + 0], acc.y + seb[c + 1]);
            hq[q * 2 + 1] = __floats2half2_rn(acc.z + seb[c + 2], acc.w + seb[c + 3]);
        }
    } else if (bid == NB_ENC) {
        for (int i = threadIdx.x; i < 2 * HPAD * 32 + 2 * HPAD; i += 256) {
            if (i < 2 * HPAD * 32) {
                int l = i / (HPAD * 32), r = i % (HPAD * 32);
                int j = r / 32, c = r % 32;
                w1tp[i] = (j < 75) ? W1[l * 2400 + c * 75 + j] : 0.f;
                w2p[i]  = (j < 75) ? W2[l * 2400 + j * 32 + c] : 0.f;
            } else {
                int k = i - 2 * HPAD * 32;
                int l = k / HPAD, j = k % HPAD;
                b1p[k] = (j < 75) ? b1[l * 75 + j] : 0.f;
            }
        }
    } else {
        int g = (bid - NB_ENC - 1) * 256 + threadIdx.x;
        if (g > N_GRAPHS) return;
        int lo = 0, hi = N_NODES;
        while (lo < hi) {
            int mid = (lo + hi) >> 1;
            if (batch[mid] < g) lo = mid + 1; else hi = mid;
        }
        goff[g] = lo;
    }
}

// ---------- bucket sort phase A: per-chunk histogram (LDS atomics only) ----------
__global__ void __launch_bounds__(256) ksA(const int* __restrict__ ei, int* __restrict__ cmat) {
    __shared__ int lh[NBKT];
    for (int i = threadIdx.x; i < NBKT; i += 256) lh[i] = 0;
    __syncthreads();
    int b0 = blockIdx.x * CHUNK;
    for (int i = threadIdx.x; i < CHUNK; i += 256) {
        int e = b0 + i;
        if (e < N_EDGES) atomicAdd(&lh[ei[N_EDGES + e] >> 8], 1);
    }
    __syncthreads();
    for (int i = threadIdx.x; i < NBKT; i += 256)
        cmat[i * NBLKA + blockIdx.x] = lh[i];
}

// ---------- 3-kernel exclusive scan of cmat ----------
__global__ void ks1(const int* __restrict__ a, int* __restrict__ bs) {
    __shared__ int s[256];
    int i = blockIdx.x * 256 + threadIdx.x;
    s[threadIdx.x] = a[i];
    __syncthreads();
    for (int o = 128; o > 0; o >>= 1) {
        if (threadIdx.x < o) s[threadIdx.x] += s[threadIdx.x + o];
        __syncthreads();
    }
    if (threadIdx.x == 0) bs[blockIdx.x] = s[0];
}

template<int NSX, int VPTX>
__global__ void ks2(int* __restrict__ bs) {
    __shared__ int s[256];
    int t = threadIdx.x;
    int v[VPTX];
    int base = t * VPTX, sum = 0;
#pragma unroll
    for (int k = 0; k < VPTX; k++) {
        int idx = base + k;
        int x = (idx < NSX) ? bs[idx] : 0;
        v[k] = sum; sum += x;
    }
    s[t] = sum;
    __syncthreads();
    for (int o = 1; o < 256; o <<= 1) {
        int add = (t >= o) ? s[t - o] : 0;
        __syncthreads();
        s[t] += add;
        __syncthreads();
    }
    int excl = (t == 0) ? 0 : s[t - 1];
#pragma unroll
    for (int k = 0; k < VPTX; k++) {
        int idx = base + k;
        if (idx < NSX) bs[idx] = excl + v[k];
    }
}

__global__ void ks3(int* __restrict__ a, const int* __restrict__ bs) {
    __shared__ int s[256];
    int t = threadIdx.x, i = blockIdx.x * 256 + t;
    int v = a[i];
    s[t] = v;
    __syncthreads();
    for (int o = 1; o < 256; o <<= 1) {
        int add = (t >= o) ? s[t - o] : 0;
        __syncthreads();
        s[t] += add;
        __syncthreads();
    }
    a[i] = s[t] - v + bs[blockIdx.x];
}

// ---------- phase B: counting sort in LDS, 8-byte quantized records + key/dl bytes ----------
__global__ void __launch_bounds__(256) ksB(const int* __restrict__ ei, const float* __restrict__ ea,
                                           const int* __restrict__ cmat, uint2* __restrict__ buf1,
                                           unsigned char* __restrict__ key) {
    __shared__ uint2 rec[CHUNK];           // 16 KB
    __shared__ unsigned short sbkt[CHUNK]; // 4 KB
    __shared__ unsigned char sdl[CHUNK];   // 2 KB
    __shared__ int lh[NBKT];
    __shared__ int lex[NBKT];
    __shared__ int gb[NBKT];
    __shared__ int sc[256];
    int t = threadIdx.x;
    int b0 = blockIdx.x * CHUNK;
    int nval = min(CHUNK, N_EDGES - b0);
    for (int i = t; i < NBKT; i += 256) lh[i] = 0;
    __syncthreads();
    for (int i = t; i < nval; i += 256)
        atomicAdd(&lh[ei[N_EDGES + b0 + i] >> 8], 1);
    __syncthreads();
    int x0 = (t * 2 < NBKT) ? lh[t * 2] : 0;
    int x1 = (t * 2 + 1 < NBKT) ? lh[t * 2 + 1] : 0;
    int v0 = 0, v1 = x0, run = x0 + x1;
    sc[t] = run;
    __syncthreads();
    for (int o = 1; o < 256; o <<= 1) {
        int add = (t >= o) ? sc[t - o] : 0;
        __syncthreads();
        sc[t] += add;
        __syncthreads();
    }
    int excl = (t == 0) ? 0 : sc[t - 1];
    if (t * 2 < NBKT) {
        int base = excl + v0;
        lex[t * 2] = base; lh[t * 2] = base;
        gb[t * 2] = cmat[(t * 2) * NBLKA + blockIdx.x];
    }
    if (t * 2 + 1 < NBKT) {
        int base = excl + v1;
        lex[t * 2 + 1] = base; lh[t * 2 + 1] = base;
        gb[t * 2 + 1] = cmat[(t * 2 + 1) * NBLKA + blockIdx.x];
    }
    __syncthreads();
    for (int i = t; i < nval; i += 256) {
        int e = b0 + i;
        int src = ei[e], dst = ei[N_EDGES + e];
        float a0 = ea[(size_t)e * 3 + 0], a1 = ea[(size_t)e * 3 + 1], a2 = ea[(size_t)e * 3 + 2];
        unsigned q0 = (unsigned)(int)(a0 * 32767.f + 0.5f);
        unsigned q1 = (unsigned)(int)(a1 * 32767.f + 0.5f);
        unsigned q2 = (unsigned)(int)(a2 * 32767.f + 0.5f);
        int bkt = dst >> 8;
        int r = atomicAdd(&lh[bkt], 1);
        rec[r] = make_uint2((unsigned)src | (q0 << 17), q1 | (q2 << 15));
        sbkt[r] = (unsigned short)bkt;
        sdl[r] = (unsigned char)(dst & 255);
    }
    __syncthreads();
    for (int p = t; p < nval; p += 256) {
        int bkt = sbkt[p];
        int gp = gb[bkt] + (p - lex[bkt]);
        buf1[gp] = rec[p];
        key[gp] = sdl[p];
    }
}

// ---------- phase C: per-256-node-bucket exact CSR (1024 thr for TLP); decode 8B -> float4 ----------
__global__ void __launch_bounds__(1024) ksC(const int* __restrict__ cmat, const uint2* __restrict__ buf1,
                                            const unsigned char* __restrict__ key,
                                            float4* __restrict__ packed, int* __restrict__ offs) {
    __shared__ int cnt[256];
    __shared__ int sc2[256];
    __shared__ int excl[256];
    int g = blockIdx.x, t = threadIdx.x;
    int bb = cmat[g * NBLKA];
    int be = (g == NBKT - 1) ? N_EDGES : cmat[(g + 1) * NBLKA];
    if (t < 256) cnt[t] = 0;
    __syncthreads();
    for (int j = bb + t; j < be; j += 1024) atomicAdd(&cnt[key[j]], 1);
    __syncthreads();
    if (t < 256) sc2[t] = cnt[t];
    __syncthreads();
    for (int o = 1; o < 256; o <<= 1) {
        int add = 0;
        if (t < 256 && t >= o) add = sc2[t - o];
        __syncthreads();
        if (t < 256) sc2[t] += add;
        __syncthreads();
    }
    if (t < 256) {
        excl[t] = sc2[t] - cnt[t];
        offs[(g << 8) + t] = bb + excl[t];
        cnt[t] = 0;
    }
    if (g == NBKT - 1 && t == 0) offs[NPAD2] = N_EDGES;
    __syncthreads();
    for (int j = bb + t; j < be; j += 1024) {
        uint2 r = buf1[j];
        int dl = key[j];
        int rank = atomicAdd(&cnt[dl], 1);
        unsigned src = r.x & 0x1FFFFu;
        float a0 = (float)(r.x >> 17) * ISC;
        float a1 = (float)(r.y & 0x7FFFu) * ISC;
        float a2 = (float)(r.y >> 15) * ISC;
        packed[bb + excl[dl] + rank] = make_float4(a0, a1, a2, __int_as_float((int)(src << 5)));
    }
}

// ---------- pull aggregation: 32 threads/node, fp16 gather (eb pre-folded), unroll-2 ----------
// packed.w = src<<5 (h16 element offset); BN=true applies relu(BN1(z)) to self-term inline
template<bool BN>
__global__ void __launch_bounds__(256) k_agg(const float4* __restrict__ packed,
                                             const int* __restrict__ offs,
                                             const float* __restrict__ eW,
                                             const __half* __restrict__ h16,
                                             const float* __restrict__ hs,
                                             const float* __restrict__ stats,
                                             const float* __restrict__ bng, const float* __restrict__ bnb,
                                             float* __restrict__ zin) {
    int t = blockIdx.x * 256 + threadIdx.x;   // N_NODES*32 exact
    int n = t >> 5, s = t & 31;
    int q = s & 7, part = s >> 3;
    int c0 = q * 4;
    float w0[4], w1[4], w2[4];
#pragma unroll
    for (int i = 0; i < 4; i++) {
        w0[i] = eW[c0 + i];
        w1[i] = eW[32 + c0 + i];
        w2[i] = eW[64 + c0 + i];
    }
    int beg = offs[n], end = offs[n + 1];
    float acc0[4] = {0.f, 0.f, 0.f, 0.f};
    float acc1[4] = {0.f, 0.f, 0.f, 0.f};
    int j = beg + part;
    for (; j + 4 < end; j += 8) {
        float4 pa = packed[j];
        float4 pb = packed[j + 4];
        unsigned offa = (unsigned)__float_as_int(pa.w) + (unsigned)c0;
        unsigned offb = (unsigned)__float_as_int(pb.w) + (unsigned)c0;
        float2 ra = *(const float2*)(h16 + offa);
        float2 rb = *(const float2*)(h16 + offb);
        float2 a01 = __half22float2(*(__half2*)&ra.x);
        float2 a23 = __half22float2(*(__half2*)&ra.y);
        float2 b01 = __half22float2(*(__half2*)&rb.x);
        float2 b23 = __half22float2(*(__half2*)&rb.y);
        float ha4[4] = {a01.x, a01.y, a23.x, a23.y};
        float hb4[4] = {b01.x, b01.y, b23.x, b23.y};
#pragma unroll
        for (int i = 0; i < 4; i++) {
            acc0[i] += fmaxf(ha4[i] + pa.x * w0[i] + pa.y * w1[i] + pa.z * w2[i], 0.f);
            acc1[i] += fmaxf(hb4[i] + pb.x * w0[i] + pb.y * w1[i] + pb.z * w2[i], 0.f);
        }
    }
    if (j < end) {
        float4 p = packed[j];
        unsigned offp = (unsigned)__float_as_int(p.w) + (unsigned)c0;
        float2 r = *(const float2*)(h16 + offp);
        float2 a01 = __half22float2(*(__half2*)&r.x);
        float2 a23 = __half22float2(*(__half2*)&r.y);
        float hp4[4] = {a01.x, a01.y, a23.x, a23.y};
#pragma unroll
        for (int i = 0; i < 4; i++)
            acc0[i] += fmaxf(hp4[i] + p.x * w0[i] + p.y * w1[i] + p.z * w2[i], 0.f);
    }
    float acc[4];
#pragma unroll
    for (int i = 0; i < 4; i++) {
        acc[i] = acc0[i] + acc1[i];
        acc[i] += __shfl_xor(acc[i], 8, 64);
        acc[i] += __shfl_xor(acc[i], 16, 64);
    }
    if (part == 0) {
        float4 hq = *(const float4*)(hs + (size_t)n * 32 + c0);   // coalesced, L2-warm
        float* hp = (float*)&hq;
        float sv[4];
        if (BN) {
            const float invN = 1.0f / (float)N_NODES;
#pragma unroll
            for (int i = 0; i < 4; i++) {
                int c = c0 + i;
                float mu = stats[c] * invN;
                float var = stats[32 + c] * invN - mu * mu;
                float scl = bng[c] / sqrtf(var + BN_EPS);
                float sft = bnb[c] - mu * scl;
                sv[i] = fmaxf(hp[i] * scl + sft, 0.f);
            }
        } else {
#pragma unroll
            for (int i = 0; i < 4; i++) sv[i] = hp[i];
        }
        *(float4*)(zin + (size_t)n * 32 + c0) =
            make_float4(acc[0] + sv[0], acc[1] + sv[1], acc[2] + sv[2], acc[3] + sv[3]);
    }
}

// ---------- fused MLP, 2 nodes/thread, named float4 regs + per-block BN partial stats ----------
__global__ void __launch_bounds__(256, 2) k_mlp(float* __restrict__ zio,
                                                const float* __restrict__ W1, const float* __restrict__ B1,
                                                const float* __restrict__ W2, const float* __restrict__ b2,
                                                float* __restrict__ pstat) {
    __shared__ float sW1[HPAD * W1S];  // 11.25 KB
    __shared__ float sW2[2560];        // 10 KB
    __shared__ float sB1[80];
    __shared__ float sb2[32];
    __shared__ float hidL[64 * 84];    // 21 KB
    __shared__ float psum[4][32];
    __shared__ float psq[4][32];
    for (int i = threadIdx.x; i < 2560; i += 256) {
        int j = i >> 5, c = i & 31;
        sW1[j * W1S + c] = W1[i];
        sW2[i] = W2[i];
    }
    if (threadIdx.x < 80) sB1[threadIdx.x] = B1[threadIdx.x];
    if (threadIdx.x < 32) sb2[threadIdx.x] = b2[threadIdx.x];
    __syncthreads();
    unsigned lane = threadIdx.x & 63;
    unsigned wv = threadIdx.x >> 6;
    unsigned oct = lane >> 3;
    unsigned nd = lane & 7;
    unsigned nA = blockIdx.x * 64 + wv * 16 + nd;
    unsigned nB = nA + 8;
    bool vA = nA < N_NODES, vB = nB < N_NODES;
    unsigned nAc = vA ? nA : (N_NODES - 1);
    unsigned nBc = vB ? nB : (N_NODES - 1);
    const float4* apA = (const float4*)(zio + (size_t)nAc * 32);
    const float4* apB = (const float4*)(zio + (size_t)nBc * 32);
    float4 zA0 = apA[0], zA1 = apA[1], zA2 = apA[2], zA3 = apA[3];
    float4 zA4 = apA[4], zA5 = apA[5], zA6 = apA[6], zA7 = apA[7];
    float4 zB0 = apB[0], zB1 = apB[1], zB2 = apB[2], zB3 = apB[3];
    float4 zB4 = apB[4], zB5 = apB[5], zB6 = apB[6], zB7 = apB[7];
    float* hrowA = &hidL[(wv * 16 + nd) * 84];
    float* hrowB = &hidL[(wv * 16 + 8 + nd) * 84];
#pragma unroll
    for (int i = 0; i < 10; i++) {
        int j = (int)oct * 10 + i;
        const float4* wp = (const float4*)(sW1 + j * W1S);
        float a0 = 0.f, a1 = 0.f, a2 = 0.f, a3 = 0.f;
        float b0 = 0.f, b1v = 0.f, b2v = 0.f, b3 = 0.f;
#define MLP_STEP(Q, ZA, ZB)                                   \
        { float4 w4 = wp[Q];                                  \
          a0 += ZA.x * w4.x; a1 += ZA.y * w4.y;               \
          a2 += ZA.z * w4.z; a3 += ZA.w * w4.w;               \
          b0 += ZB.x * w4.x; b1v += ZB.y * w4.y;              \
          b2v += ZB.z * w4.z; b3 += ZB.w * w4.w; }
        MLP_STEP(0, zA0, zB0)
        MLP_STEP(1, zA1, zB1)
        MLP_STEP(2, zA2, zB2)
        MLP_STEP(3, zA3, zB3)
        MLP_STEP(4, zA4, zB4)
        MLP_STEP(5, zA5, zB5)
        MLP_STEP(6, zA6, zB6)
        MLP_STEP(7, zA7, zB7)
#undef MLP_STEP
        float bias = sB1[j];
        hrowA[oct * 10 + i] = fmaxf(bias + ((a0 + a1) + (a2 + a3)), 0.f);
        hrowB[oct * 10 + i] = fmaxf(bias + ((b0 + b1v) + (b2v + b3)), 0.f);
    }
    float4 zoA = *(const float4*)(sb2 + oct * 4);
    float4 zoB = zoA;
    const float4* hvA4 = (const float4*)hrowA;
    const float4* hvB4 = (const float4*)hrowB;
#pragma unroll
    for (int k = 0; k < 20; k++) {
        float4 ha = hvA4[k];
        float4 hb = hvB4[k];
        const float* wr = sW2 + (k * 4) * 32 + oct * 4;
        float4 wa = *(const float4*)(wr);
        float4 wb = *(const float4*)(wr + 32);
        float4 wc = *(const float4*)(wr + 64);
        float4 wd = *(const float4*)(wr + 96);
        zoA.x += ha.x * wa.x + ha.y * wb.x + ha.z * wc.x + ha.w * wd.x;
        zoA.y += ha.x * wa.y + ha.y * wb.y + ha.z * wc.y + ha.w * wd.y;
        zoA.z += ha.x * wa.z + ha.y * wb.z + ha.z * wc.z + ha.w * wd.z;
        zoA.w += ha.x * wa.w + ha.y * wb.w + ha.z * wc.w + ha.w * wd.w;
        zoB.x += hb.x * wa.x + hb.y * wb.x + hb.z * wc.x + hb.w * wd.x;
        zoB.y += hb.x * wa.y + hb.y * wb.y + hb.z * wc.y + hb.w * wd.y;
        zoB.z += hb.x * wa.z + hb.y * wb.z + hb.z * wc.z + hb.w * wd.z;
        zoB.w += hb.x * wa.w + hb.y * wb.w + hb.z * wc.w + hb.w * wd.w;
    }
    if (vA) *(float4*)(zio + (size_t)nA * 32 + oct * 4) = zoA;
    if (vB) *(float4*)(zio + (size_t)nB * 32 + oct * 4) = zoB;
    float s0 = (vA ? zoA.x : 0.f) + (vB ? zoB.x : 0.f);
    float s1 = (vA ? zoA.y : 0.f) + (vB ? zoB.y : 0.f);
    float s2 = (vA ? zoA.z : 0.f) + (vB ? zoB.z : 0.f);
    float s3 = (vA ? zoA.w : 0.f) + (vB ? zoB.w : 0.f);
    float q0 = (vA ? zoA.x * zoA.x : 0.f) + (vB ? zoB.x * zoB.x : 0.f);
    float q1 = (vA ? zoA.y * zoA.y : 0.f) + (vB ? zoB.y * zoB.y : 0.f);
    float q2 = (vA ? zoA.z * zoA.z : 0.f) + (vB ? zoB.z * zoB.z : 0.f);
    float q3 = (vA ? zoA.w * zoA.w : 0.f) + (vB ? zoB.w * zoB.w : 0.f);
#pragma unroll
    for (int m = 1; m < 8; m <<= 1) {
        s0 += __shfl_xor(s0, m, 64); s1 += __shfl_xor(s1, m, 64);
        s2 += __shfl_xor(s2, m, 64); s3 += __shfl_xor(s3, m, 64);
        q0 += __shfl_xor(q0, m, 64); q1 += __shfl_xor(q1, m, 64);
        q2 += __shfl_xor(q2, m, 64); q3 += __shfl_xor(q3, m, 64);
    }
    if (nd == 0) {
        psum[wv][oct * 4 + 0] = s0; psum[wv][oct * 4 + 1] = s1;
        psum[wv][oct * 4 + 2] = s2; psum[wv][oct * 4 + 3] = s3;
        psq[wv][oct * 4 + 0] = q0;  psq[wv][oct * 4 + 1] = q1;
        psq[wv][oct * 4 + 2] = q2;  psq[wv][oct * 4 + 3] = q3;
    }
    __syncthreads();
    if (threadIdx.x < 32) {
        int c = threadIdx.x;
        pstat[(size_t)c * PSROW + blockIdx.x] =
            psum[0][c] + psum[1][c] + psum[2][c] + psum[3][c];
    } else if (threadIdx.x < 64) {
        int c = threadIdx.x - 32;
        pstat[(size_t)(32 + c) * PSROW + blockIdx.x] =
            psq[0][c] + psq[1][c] + psq[2][c] + psq[3][c];
    }
}

// ---------- stats reducer: 64 blocks, coalesced row sums ----------
__global__ void __launch_bounds__(256) k_statsR(const float* __restrict__ pstat, float* __restrict__ stats) {
    __shared__ float ls[4];
    int r = blockIdx.x;
    const float* row = pstat + (size_t)r * PSROW;
    float s = 0.f;
    for (int i = threadIdx.x; i < NBMLP; i += 256) s += row[i];
#pragma unroll
    for (int m = 1; m < 64; m <<= 1) s += __shfl_xor(s, m, 64);
    if ((threadIdx.x & 63) == 0) ls[threadIdx.x >> 6] = s;
    __syncthreads();
    if (threadIdx.x == 0) stats[r] = ls[0] + ls[1] + ls[2] + ls[3];
}

// ---------- BN apply + relu + eb fold, fp16 mirror only (layer-1) ----------
__global__ void k_bnh(const float* __restrict__ z, __half* __restrict__ m,
                      const float* __restrict__ stats, const float* __restrict__ g,
                      const float* __restrict__ b, const float* __restrict__ eb) {
    int t = blockIdx.x * 256 + threadIdx.x;
    if (t >= N_NODES * 8) return;
    int q = t & 7;
    float4 zv = ((const float4*)z)[t];
    float* zp = (float*)&zv;
    float ov[4];
    const float invN = 1.0f / (float)N_NODES;
#pragma unroll
    for (int i = 0; i < 4; i++) {
        int c = q * 4 + i;
        float mu = stats[c] * invN;
        float var = stats[32 + c] * invN - mu * mu;
        float sc = g[c] / sqrtf(var + BN_EPS);
        ov[i] = fmaxf((zp[i] - mu) * sc + b[c], 0.f) + eb[c];
    }
    __half2* hq = (__half2*)(m + (size_t)t * 4);
    hq[0] = __floats2half2_rn(ov[0], ov[1]);
    hq[1] = __floats2half2_rn(ov[2], ov[3]);
}

// ---------- fused mean-pool (BN2+relu inline) + head MLP: one wave per graph ----------
__global__ void __launch_bounds__(256) k_poolhead(const float* __restrict__ z, const int* __restrict__ goff,
                                                  const float* __restrict__ stats,
                                                  const float* __restrict__ bg, const float* __restrict__ bb,
                                                  const float* __restrict__ W1, const float* __restrict__ b1,
                                                  const float* __restrict__ W2, const float* __restrict__ b2,
                                                  float* __restrict__ out) {
    __shared__ float sW1[512];
    __shared__ float sb1[16], sW2[32], sb2[2];
    __shared__ float gxs[4][32];
    for (int i = threadIdx.x; i < 512; i += 256) sW1[i] = W1[i];
    if (threadIdx.x < 16) sb1[threadIdx.x] = b1[threadIdx.x];
    if (threadIdx.x < 32) sW2[threadIdx.x] = W2[threadIdx.x];
    if (threadIdx.x < 2) sb2[threadIdx.x] = b2[threadIdx.x];
    __syncthreads();
    int wid = threadIdx.x >> 6, lane = threadIdx.x & 63;
    int gi = blockIdx.x * 4 + wid;
    int s = goff[gi], e = goff[gi + 1];
    int c = lane & 31, half = lane >> 5;
    const float invN = 1.0f / (float)N_NODES;
    float mu = stats[c] * invN;
    float var = stats[32 + c] * invN - mu * mu;
    float scl = bg[c] / sqrtf(var + BN_EPS);
    float sft = bb[c] - mu * scl;
    float acc = 0.f;
    for (int n = s + half; n < e; n += 2)
        acc += fmaxf(z[(size_t)n * 32 + c] * scl + sft, 0.f);
    acc += __shfl_down(acc, 32, 64);
    float inv = 1.0f / fmaxf((float)(e - s), 1.0f);
    if (lane < 32) gxs[wid][c] = acc * inv;
    float hid = 0.f;
    if (lane < 16) {
        float a = sb1[lane];
#pragma unroll
        for (int cc = 0; cc < 32; cc++) a += gxs[wid][cc] * sW1[cc * 16 + lane];
        hid = fmaxf(a, 0.f);
    }
    float p0 = 0.f, p1 = 0.f;
    if (lane < 16) { p0 = hid * sW2[lane * 2 + 0]; p1 = hid * sW2[lane * 2 + 1]; }
#pragma unroll
    for (int m = 1; m < 16; m <<= 1) {
        p0 += __shfl_xor(p0, m, 64);
        p1 += __shfl_xor(p1, m, 64);
    }
    if (lane == 0) {
        out[(size_t)gi * 2 + 0] = p0 + sb2[0];
        out[(size_t)gi * 2 + 1] = p1 + sb2[1];
    }
}

extern "C" void kernel_launch(void* const* d_in, const int* in_sizes, int n_in,
                              void* d_out, int out_size, void* d_ws, size_t ws_size,
                              hipStream_t stream) {
    const float* x       = (const float*)d_in[0];
    const int*   ei      = (const int*)d_in[1];
    const float* eattr   = (const float*)d_in[2];
    const int*   batch   = (const int*)d_in[3];
    const float* node_w  = (const float*)d_in[4];
    const float* node_b  = (const float*)d_in[5];
    const float* edge_w  = (const float*)d_in[6];
    const float* edge_b  = (const float*)d_in[7];
    const float* conv_w1 = (const float*)d_in[8];
    const float* conv_b1 = (const float*)d_in[9];
    const float* conv_w2 = (const float*)d_in[10];
    const float* conv_b2 = (const float*)d_in[11];
    const float* bn_g    = (const float*)d_in[12];
    const float* bn_b    = (const float*)d_in[13];
    const float* lin1_w  = (const float*)d_in[14];
    const float* lin1_b  = (const float*)d_in[15];
    const float* lin2_w  = (const float*)d_in[16];
    const float* lin2_b  = (const float*)d_in[17];
    float* out = (float*)d_out;

    uint2*  buf1    = (uint2*)d_ws;                         // 25.6 MB (8-B quantized records)
    float4* packed  = (float4*)(buf1 + N_EDGES);            // 51.2 MB
    float*  h       = (float*)(packed + N_EDGES);           // 12.8 MB (h0, then zin2/z2)
    float*  agg     = h + (size_t)N_NODES * 32;             // 12.8 MB (zin1/z1)
    __half* m16     = (__half*)(agg + (size_t)N_NODES * 32);// 6.4 MB (h0+eb mirror, then BN1+eb mirror)
    unsigned char* key = (unsigned char*)(m16 + (size_t)N_NODES * 32); // 3.2 MB
    int*    cmat    = (int*)(key + N_EDGES);                // LALLOC ints
    float*  stats   = (float*)(cmat + LALLOC);              // 128 floats
    int*    t1      = (int*)(stats + 128);                  // 2560
    int*    offs    = t1 + 2560;                            // NPAD2+1
    int*    goff    = offs + NPAD2 + 1;                     // N_GRAPHS+1
    float*  pstat   = (float*)(goff + N_GRAPHS + 1);        // 64*PSROW
    float*  w1tp    = pstat + 64 * PSROW;                   // 2*80*32
    float*  b1p     = w1tp + 2 * HPAD * 32;                 // 2*80
    float*  w2p     = b1p + 2 * HPAD;                       // 2*80*32

    int nb_vec = (N_NODES * 8 + 255) / 256;

    hipMemsetAsync(cmat + NBLK_TOT, 0, (size_t)(LALLOC - NBLK_TOT + 128) * sizeof(int), stream);
    k_setup<<<NB_ENC + 1 + NB_GOFF, 256, 0, stream>>>(x, node_w, node_b, edge_b, h, m16,
                                                      conv_w1, conv_b1, conv_w2, w1tp, b1p, w2p,
                                                      batch, goff);

    ksA<<<NBLKA, 256, 0, stream>>>(ei, cmat);
    ks1<<<NS1, 256, 0, stream>>>(cmat, t1);
    ks2<NS1, 10><<<1, 256, 0, stream>>>(t1);
    ks3<<<NS1, 256, 0, stream>>>(cmat, t1);
    ksB<<<NBLKA, 256, 0, stream>>>(ei, eattr, cmat, buf1, key);
    ksC<<<NBKT, 1024, 0, stream>>>(cmat, buf1, key, packed, offs);

    // layer 1
    k_agg<false><<<N_NODES * 32 / 256, 256, 0, stream>>>(packed, offs, edge_w,
                                                         m16, h, stats, bn_g, bn_b, agg);
    k_mlp<<<NBMLP, 256, 0, stream>>>(agg, w1tp, b1p, w2p, conv_b2, pstat);
    k_statsR<<<64, 256, 0, stream>>>(pstat, stats);
    k_bnh<<<nb_vec, 256, 0, stream>>>(agg, m16, stats, bn_g, bn_b, edge_b);
    // layer 2
    k_agg<true><<<N_NODES * 32 / 256, 256, 0, stream>>>(packed, offs, edge_w,
                                                        m16, agg, stats, bn_g, bn_b, h);
    k_mlp<<<NBMLP, 256, 0, stream>>>(h, w1tp + HPAD * 32, b1p + HPAD,
                                     w2p + HPAD * 32, conv_b2 + 32, pstat);
    k_statsR<<<64, 256, 0, stream>>>(pstat, stats + 64);
    k_poolhead<<<N_GRAPHS / 4, 256, 0, stream>>>(h, goff, stats + 64, bn_g + 32, bn_b + 32,
                                                 lin1_w, lin1_b, lin2_w, lin2_b, out);
}

// Round 12
// 421.162 us; speedup vs baseline: 1.0909x; 1.0317x over previous
//
#include <hip/hip_runtime.h>
#include <hip/hip_fp16.h>

#define N_NODES 100000
#define N_EDGES 3200000
#define N_GRAPHS 5000
#define BN_EPS 1e-5f
#define HPAD 80        // hidden 75 padded to 80
#define CHUNK 2048     // edges per bucket-sort block
#define NBLKA 1563     // ceil(N_EDGES / CHUNK)
#define NBKT 392       // buckets of 256 nodes (dst >> 8)
#define NPAD2 (NBKT * 256)     // 100352
#define NBLK_TOT (NBKT * NBLKA)  // 612696
#define NS1 2394       // ceil(NBLK_TOT / 256)
#define LALLOC (NS1 * 256)
#define W1S 36         // sW1 row stride: 2-way bank alias only (free)
#define NB_ENC 391     // encode blocks in k_front
#define NB_GOFF 20     // goff blocks in k_front
#define NBMLP 1563     // k_mlp grid: 2 nodes/thread, 64 nodes/block
#define PSROW 1568     // pstat row stride (padded)
#define ISC (1.0f / 32767.0f)   // attr dequant scale (folded into eW in k_agg)

// ---------- fused front: bucket histogram (+pad zero) + node encoder + weight prep + goff ----------
__global__ void __launch_bounds__(256) k_front(const int* __restrict__ ei, int* __restrict__ cmat,
                                               const float* __restrict__ x, const float* __restrict__ nW,
                                               const float* __restrict__ nb, const float* __restrict__ eb,
                                               float* __restrict__ h, __half* __restrict__ h16,
                                               const float* __restrict__ W1, const float* __restrict__ b1,
                                               const float* __restrict__ W2,
                                               float* __restrict__ w1tp, float* __restrict__ b1p,
                                               float* __restrict__ w2p,
                                               const int* __restrict__ batch, int* __restrict__ goff) {
    int bid = blockIdx.x;
    if (bid < NBLKA) {
        // ---- ksA role: per-chunk histogram (LDS atomics only) ----
        __shared__ int lh[NBKT];
        if (bid == 0) {   // zero the scan pad tail (disjoint from all histogram writes)
            for (int i = threadIdx.x; i < LALLOC - NBLK_TOT; i += 256)
                cmat[NBLK_TOT + i] = 0;
        }
        for (int i = threadIdx.x; i < NBKT; i += 256) lh[i] = 0;
        __syncthreads();
        int b0 = bid * CHUNK;
        for (int i = threadIdx.x; i < CHUNK; i += 256) {
            int e = b0 + i;
            if (e < N_EDGES) atomicAdd(&lh[ei[N_EDGES + e] >> 8], 1);
        }
        __syncthreads();
        for (int i = threadIdx.x; i < NBKT; i += 256)
            cmat[i * NBLKA + bid] = lh[i];
    } else if (bid < NBLKA + NB_ENC) {
        // ---- encoder role: h = x @ nW + nb (fp32) ; m16 = h + eb (fp16) ----
        __shared__ float sW[448];
        __shared__ float sb[32];
        __shared__ float seb[32];
        for (int i = threadIdx.x; i < 448; i += 256) sW[i] = nW[i];
        if (threadIdx.x < 32) { sb[threadIdx.x] = nb[threadIdx.x]; seb[threadIdx.x] = eb[threadIdx.x]; }
        __syncthreads();
        int n = (bid - NBLKA) * 256 + threadIdx.x;
        if (n >= N_NODES) return;
        float xi[14];
#pragma unroll
        for (int k = 0; k < 14; k++) xi[k] = x[n * 14 + k];
        float4* hp = (float4*)(h + (size_t)n * 32);
        __half2* hq = (__half2*)(h16 + (size_t)n * 32);
#pragma unroll
        for (int q = 0; q < 8; q++) {
            float4 acc;
            float* ap = (float*)&acc;
#pragma unroll
            for (int i = 0; i < 4; i++) {
                int c = q * 4 + i;
                float a = sb[c];
#pragma unroll
                for (int k = 0; k < 14; k++) a += xi[k] * sW[k * 32 + c];
                ap[i] = a;
            }
            hp[q] = acc;
            int c = q * 4;
            hq[q * 2 + 0] = __floats2half2_rn(acc.x + seb[c + 0], acc.y + seb[c + 1]);
            hq[q * 2 + 1] = __floats2half2_rn(acc.z + seb[c + 2], acc.w + seb[c + 3]);
        }
    } else if (bid == NBLKA + NB_ENC) {
        // ---- weight prep role ----
        for (int i = threadIdx.x; i < 2 * HPAD * 32 + 2 * HPAD; i += 256) {
            if (i < 2 * HPAD * 32) {
                int l = i / (HPAD * 32), r = i % (HPAD * 32);
                int j = r / 32, c = r % 32;
                w1tp[i] = (j < 75) ? W1[l * 2400 + c * 75 + j] : 0.f;
                w2p[i]  = (j < 75) ? W2[l * 2400 + j * 32 + c] : 0.f;
            } else {
                int k = i - 2 * HPAD * 32;
                int l = k / HPAD, j = k % HPAD;
                b1p[k] = (j < 75) ? b1[l * 75 + j] : 0.f;
            }
        }
    } else {
        // ---- goff role: one binary search per thread ----
        int g = (bid - NBLKA - NB_ENC - 1) * 256 + threadIdx.x;
        if (g > N_GRAPHS) return;
        int lo = 0, hi = N_NODES;
        while (lo < hi) {
            int mid = (lo + hi) >> 1;
            if (batch[mid] < g) lo = mid + 1; else hi = mid;
        }
        goff[g] = lo;
    }
}

// ---------- 3-kernel exclusive scan of cmat ----------
__global__ void ks1(const int* __restrict__ a, int* __restrict__ bs) {
    __shared__ int s[256];
    int i = blockIdx.x * 256 + threadIdx.x;
    s[threadIdx.x] = a[i];
    __syncthreads();
    for (int o = 128; o > 0; o >>= 1) {
        if (threadIdx.x < o) s[threadIdx.x] += s[threadIdx.x + o];
        __syncthreads();
    }
    if (threadIdx.x == 0) bs[blockIdx.x] = s[0];
}

template<int NSX, int VPTX>
__global__ void ks2(int* __restrict__ bs) {
    __shared__ int s[256];
    int t = threadIdx.x;
    int v[VPTX];
    int base = t * VPTX, sum = 0;
#pragma unroll
    for (int k = 0; k < VPTX; k++) {
        int idx = base + k;
        int x = (idx < NSX) ? bs[idx] : 0;
        v[k] = sum; sum += x;
    }
    s[t] = sum;
    __syncthreads();
    for (int o = 1; o < 256; o <<= 1) {
        int add = (t >= o) ? s[t - o] : 0;
        __syncthreads();
        s[t] += add;
        __syncthreads();
    }
    int excl = (t == 0) ? 0 : s[t - 1];
#pragma unroll
    for (int k = 0; k < VPTX; k++) {
        int idx = base + k;
        if (idx < NSX) bs[idx] = excl + v[k];
    }
}

__global__ void ks3(int* __restrict__ a, const int* __restrict__ bs) {
    __shared__ int s[256];
    int t = threadIdx.x, i = blockIdx.x * 256 + t;
    int v = a[i];
    s[t] = v;
    __syncthreads();
    for (int o = 1; o < 256; o <<= 1) {
        int add = (t >= o) ? s[t - o] : 0;
        __syncthreads();
        s[t] += add;
        __syncthreads();
    }
    a[i] = s[t] - v + bs[blockIdx.x];
}

// ---------- phase B: counting sort in LDS, 8-byte quantized records + key/dl bytes ----------
// record: w0 = src(17) | q0(15)<<17 ; w1 = q1(15) | q2(15)<<15 ; attrs in [0,1) -> 15-bit fixed point
__global__ void __launch_bounds__(256) ksB(const int* __restrict__ ei, const float* __restrict__ ea,
                                           const int* __restrict__ cmat, uint2* __restrict__ buf1,
                                           unsigned char* __restrict__ key) {
    __shared__ uint2 rec[CHUNK];           // 16 KB
    __shared__ unsigned short sbkt[CHUNK]; // 4 KB
    __shared__ unsigned char sdl[CHUNK];   // 2 KB
    __shared__ int lh[NBKT];
    __shared__ int lex[NBKT];
    __shared__ int gb[NBKT];
    __shared__ int sc[256];
    int t = threadIdx.x;
    int b0 = blockIdx.x * CHUNK;
    int nval = min(CHUNK, N_EDGES - b0);
    for (int i = t; i < NBKT; i += 256) lh[i] = 0;
    __syncthreads();
    for (int i = t; i < nval; i += 256)
        atomicAdd(&lh[ei[N_EDGES + b0 + i] >> 8], 1);
    __syncthreads();
    int x0 = (t * 2 < NBKT) ? lh[t * 2] : 0;
    int x1 = (t * 2 + 1 < NBKT) ? lh[t * 2 + 1] : 0;
    int v0 = 0, v1 = x0, run = x0 + x1;
    sc[t] = run;
    __syncthreads();
    for (int o = 1; o < 256; o <<= 1) {
        int add = (t >= o) ? sc[t - o] : 0;
        __syncthreads();
        sc[t] += add;
        __syncthreads();
    }
    int excl = (t == 0) ? 0 : sc[t - 1];
    if (t * 2 < NBKT) {
        int base = excl + v0;
        lex[t * 2] = base; lh[t * 2] = base;
        gb[t * 2] = cmat[(t * 2) * NBLKA + blockIdx.x];
    }
    if (t * 2 + 1 < NBKT) {
        int base = excl + v1;
        lex[t * 2 + 1] = base; lh[t * 2 + 1] = base;
        gb[t * 2 + 1] = cmat[(t * 2 + 1) * NBLKA + blockIdx.x];
    }
    __syncthreads();
    for (int i = t; i < nval; i += 256) {
        int e = b0 + i;
        int src = ei[e], dst = ei[N_EDGES + e];
        float a0 = ea[(size_t)e * 3 + 0], a1 = ea[(size_t)e * 3 + 1], a2 = ea[(size_t)e * 3 + 2];
        unsigned q0 = (unsigned)(int)(a0 * 32767.f + 0.5f);
        unsigned q1 = (unsigned)(int)(a1 * 32767.f + 0.5f);
        unsigned q2 = (unsigned)(int)(a2 * 32767.f + 0.5f);
        int bkt = dst >> 8;
        int r = atomicAdd(&lh[bkt], 1);
        rec[r] = make_uint2((unsigned)src | (q0 << 17), q1 | (q2 << 15));
        sbkt[r] = (unsigned short)bkt;
        sdl[r] = (unsigned char)(dst & 255);
    }
    __syncthreads();
    for (int p = t; p < nval; p += 256) {
        int bkt = sbkt[p];
        int gp = gb[bkt] + (p - lex[bkt]);
        buf1[gp] = rec[p];
        key[gp] = sdl[p];
    }
}

// ---------- phase C: per-256-node-bucket exact CSR; pure reorder of 8B records ----------
__global__ void __launch_bounds__(1024) ksC(const int* __restrict__ cmat, const uint2* __restrict__ buf1,
                                            const unsigned char* __restrict__ key,
                                            uint2* __restrict__ packed, int* __restrict__ offs) {
    __shared__ int cnt[256];
    __shared__ int sc2[256];
    __shared__ int excl[256];
    int g = blockIdx.x, t = threadIdx.x;
    int bb = cmat[g * NBLKA];
    int be = (g == NBKT - 1) ? N_EDGES : cmat[(g + 1) * NBLKA];
    if (t < 256) cnt[t] = 0;
    __syncthreads();
    for (int j = bb + t; j < be; j += 1024) atomicAdd(&cnt[key[j]], 1);
    __syncthreads();
    if (t < 256) sc2[t] = cnt[t];
    __syncthreads();
    for (int o = 1; o < 256; o <<= 1) {
        int add = 0;
        if (t < 256 && t >= o) add = sc2[t - o];
        __syncthreads();
        if (t < 256) sc2[t] += add;
        __syncthreads();
    }
    if (t < 256) {
        excl[t] = sc2[t] - cnt[t];
        offs[(g << 8) + t] = bb + excl[t];
        cnt[t] = 0;
    }
    if (g == NBKT - 1 && t == 0) offs[NPAD2] = N_EDGES;
    __syncthreads();
    for (int j = bb + t; j < be; j += 1024) {
        uint2 r = buf1[j];
        int dl = key[j];
        int rank = atomicAdd(&cnt[dl], 1);
        packed[bb + excl[dl] + rank] = r;
    }
}

// ---------- pull aggregation: 32 threads/node, 8B records, inline dequant (ISC folded into eW) ----------
// BN=true applies relu(BN1(z)) to self-term inline
template<bool BN>
__global__ void __launch_bounds__(256) k_agg(const uint2* __restrict__ packed,
                                             const int* __restrict__ offs,
                                             const float* __restrict__ eW,
                                             const __half* __restrict__ h16,
                                             const float* __restrict__ hs,
                                             const float* __restrict__ stats,
                                             const float* __restrict__ bng, const float* __restrict__ bnb,
                                             float* __restrict__ zin) {
    int t = blockIdx.x * 256 + threadIdx.x;   // N_NODES*32 exact
    int n = t >> 5, s = t & 31;
    int q = s & 7, part = s >> 3;
    int c0 = q * 4;
    float w0[4], w1[4], w2[4];
#pragma unroll
    for (int i = 0; i < 4; i++) {
        w0[i] = eW[c0 + i] * ISC;        // dequant scale folded into weights
        w1[i] = eW[32 + c0 + i] * ISC;
        w2[i] = eW[64 + c0 + i] * ISC;
    }
    int beg = offs[n], end = offs[n + 1];
    float acc0[4] = {0.f, 0.f, 0.f, 0.f};
    float acc1[4] = {0.f, 0.f, 0.f, 0.f};
    int j = beg + part;
    for (; j + 4 < end; j += 8) {
        uint2 pa = packed[j];
        uint2 pb = packed[j + 4];
        unsigned offa = ((pa.x & 0x1FFFFu) << 5) + (unsigned)c0;
        unsigned offb = ((pb.x & 0x1FFFFu) << 5) + (unsigned)c0;
        float2 ra = *(const float2*)(h16 + offa);
        float2 rb = *(const float2*)(h16 + offb);
        float aq0 = (float)(pa.x >> 17), aq1 = (float)(pa.y & 0x7FFFu), aq2 = (float)(pa.y >> 15);
        float bq0 = (float)(pb.x >> 17), bq1 = (float)(pb.y & 0x7FFFu), bq2 = (float)(pb.y >> 15);
        float2 a01 = __half22float2(*(__half2*)&ra.x);
        float2 a23 = __half22float2(*(__half2*)&ra.y);
        float2 b01 = __half22float2(*(__half2*)&rb.x);
        float2 b23 = __half22float2(*(__half2*)&rb.y);
        float ha4[4] = {a01.x, a01.y, a23.x, a23.y};
        float hb4[4] = {b01.x, b01.y, b23.x, b23.y};
#pragma unroll
        for (int i = 0; i < 4; i++) {
            acc0[i] += fmaxf(ha4[i] + aq0 * w0[i] + aq1 * w1[i] + aq2 * w2[i], 0.f);
            acc1[i] += fmaxf(hb4[i] + bq0 * w0[i] + bq1 * w1[i] + bq2 * w2[i], 0.f);
        }
    }
    if (j < end) {
        uint2 p = packed[j];
        unsigned offp = ((p.x & 0x1FFFFu) << 5) + (unsigned)c0;
        float2 r = *(const float2*)(h16 + offp);
        float pq0 = (float)(p.x >> 17), pq1 = (float)(p.y & 0x7FFFu), pq2 = (float)(p.y >> 15);
        float2 a01 = __half22float2(*(__half2*)&r.x);
        float2 a23 = __half22float2(*(__half2*)&r.y);
        float hp4[4] = {a01.x, a01.y, a23.x, a23.y};
#pragma unroll
        for (int i = 0; i < 4; i++)
            acc0[i] += fmaxf(hp4[i] + pq0 * w0[i] + pq1 * w1[i] + pq2 * w2[i], 0.f);
    }
    float acc[4];
#pragma unroll
    for (int i = 0; i < 4; i++) {
        acc[i] = acc0[i] + acc1[i];
        acc[i] += __shfl_xor(acc[i], 8, 64);
        acc[i] += __shfl_xor(acc[i], 16, 64);
    }
    if (part == 0) {
        float4 hq = *(const float4*)(hs + (size_t)n * 32 + c0);   // coalesced, L2-warm
        float* hp = (float*)&hq;
        float sv[4];
        if (BN) {
            const float invN = 1.0f / (float)N_NODES;
#pragma unroll
            for (int i = 0; i < 4; i++) {
                int c = c0 + i;
                float mu = stats[c] * invN;
                float var = stats[32 + c] * invN - mu * mu;
                float scl = bng[c] / sqrtf(var + BN_EPS);
                float sft = bnb[c] - mu * scl;
                sv[i] = fmaxf(hp[i] * scl + sft, 0.f);
            }
        } else {
#pragma unroll
            for (int i = 0; i < 4; i++) sv[i] = hp[i];
        }
        *(float4*)(zin + (size_t)n * 32 + c0) =
            make_float4(acc[0] + sv[0], acc[1] + sv[1], acc[2] + sv[2], acc[3] + sv[3]);
    }
}

// ---------- fused MLP, 2 nodes/thread, named float4 regs + per-block BN partial stats ----------
__global__ void __launch_bounds__(256, 2) k_mlp(float* __restrict__ zio,
                                                const float* __restrict__ W1, const float* __restrict__ B1,
                                                const float* __restrict__ W2, const float* __restrict__ b2,
                                                float* __restrict__ pstat) {
    __shared__ float sW1[HPAD * W1S];  // 11.25 KB
    __shared__ float sW2[2560];        // 10 KB
    __shared__ float sB1[80];
    __shared__ float sb2[32];
    __shared__ float hidL[64 * 84];    // 21 KB
    __shared__ float psum[4][32];
    __shared__ float psq[4][32];
    for (int i = threadIdx.x; i < 2560; i += 256) {
        int j = i >> 5, c = i & 31;
        sW1[j * W1S + c] = W1[i];
        sW2[i] = W2[i];
    }
    if (threadIdx.x < 80) sB1[threadIdx.x] = B1[threadIdx.x];
    if (threadIdx.x < 32) sb2[threadIdx.x] = b2[threadIdx.x];
    __syncthreads();
    unsigned lane = threadIdx.x & 63;
    unsigned wv = threadIdx.x >> 6;
    unsigned oct = lane >> 3;
    unsigned nd = lane & 7;
    unsigned nA = blockIdx.x * 64 + wv * 16 + nd;
    unsigned nB = nA + 8;
    bool vA = nA < N_NODES, vB = nB < N_NODES;
    unsigned nAc = vA ? nA : (N_NODES - 1);
    unsigned nBc = vB ? nB : (N_NODES - 1);
    const float4* apA = (const float4*)(zio + (size_t)nAc * 32);
    const float4* apB = (const float4*)(zio + (size_t)nBc * 32);
    float4 zA0 = apA[0], zA1 = apA[1], zA2 = apA[2], zA3 = apA[3];
    float4 zA4 = apA[4], zA5 = apA[5], zA6 = apA[6], zA7 = apA[7];
    float4 zB0 = apB[0], zB1 = apB[1], zB2 = apB[2], zB3 = apB[3];
    float4 zB4 = apB[4], zB5 = apB[5], zB6 = apB[6], zB7 = apB[7];
    float* hrowA = &hidL[(wv * 16 + nd) * 84];
    float* hrowB = &hidL[(wv * 16 + 8 + nd) * 84];
#pragma unroll
    for (int i = 0; i < 10; i++) {
        int j = (int)oct * 10 + i;
        const float4* wp = (const float4*)(sW1 + j * W1S);
        float a0 = 0.f, a1 = 0.f, a2 = 0.f, a3 = 0.f;
        float b0 = 0.f, b1v = 0.f, b2v = 0.f, b3 = 0.f;
#define MLP_STEP(Q, ZA, ZB)                                   \
        { float4 w4 = wp[Q];                                  \
          a0 += ZA.x * w4.x; a1 += ZA.y * w4.y;               \
          a2 += ZA.z * w4.z; a3 += ZA.w * w4.w;               \
          b0 += ZB.x * w4.x; b1v += ZB.y * w4.y;              \
          b2v += ZB.z * w4.z; b3 += ZB.w * w4.w; }
        MLP_STEP(0, zA0, zB0)
        MLP_STEP(1, zA1, zB1)
        MLP_STEP(2, zA2, zB2)
        MLP_STEP(3, zA3, zB3)
        MLP_STEP(4, zA4, zB4)
        MLP_STEP(5, zA5, zB5)
        MLP_STEP(6, zA6, zB6)
        MLP_STEP(7, zA7, zB7)
#undef MLP_STEP
        float bias = sB1[j];
        hrowA[oct * 10 + i] = fmaxf(bias + ((a0 + a1) + (a2 + a3)), 0.f);
        hrowB[oct * 10 + i] = fmaxf(bias + ((b0 + b1v) + (b2v + b3)), 0.f);
    }
    float4 zoA = *(const float4*)(sb2 + oct * 4);
    float4 zoB = zoA;
    const float4* hvA4 = (const float4*)hrowA;
    const float4* hvB4 = (const float4*)hrowB;
#pragma unroll
    for (int k = 0; k < 20; k++) {
        float4 ha = hvA4[k];
        float4 hb = hvB4[k];
        const float* wr = sW2 + (k * 4) * 32 + oct * 4;
        float4 wa = *(const float4*)(wr);
        float4 wb = *(const float4*)(wr + 32);
        float4 wc = *(const float4*)(wr + 64);
        float4 wd = *(const float4*)(wr + 96);
        zoA.x += ha.x * wa.x + ha.y * wb.x + ha.z * wc.x + ha.w * wd.x;
        zoA.y += ha.x * wa.y + ha.y * wb.y + ha.z * wc.y + ha.w * wd.y;
        zoA.z += ha.x * wa.z + ha.y * wb.z + ha.z * wc.z + ha.w * wd.z;
        zoA.w += ha.x * wa.w + ha.y * wb.w + ha.z * wc.w + ha.w * wd.w;
        zoB.x += hb.x * wa.x + hb.y * wb.x + hb.z * wc.x + hb.w * wd.x;
        zoB.y += hb.x * wa.y + hb.y * wb.y + hb.z * wc.y + hb.w * wd.y;
        zoB.z += hb.x * wa.z + hb.y * wb.z + hb.z * wc.z + hb.w * wd.z;
        zoB.w += hb.x * wa.w + hb.y * wb.w + hb.z * wc.w + hb.w * wd.w;
    }
    if (vA) *(float4*)(zio + (size_t)nA * 32 + oct * 4) = zoA;
    if (vB) *(float4*)(zio + (size_t)nB * 32 + oct * 4) = zoB;
    float s0 = (vA ? zoA.x : 0.f) + (vB ? zoB.x : 0.f);
    float s1 = (vA ? zoA.y : 0.f) + (vB ? zoB.y : 0.f);
    float s2 = (vA ? zoA.z : 0.f) + (vB ? zoB.z : 0.f);
    float s3 = (vA ? zoA.w : 0.f) + (vB ? zoB.w : 0.f);
    float q0 = (vA ? zoA.x * zoA.x : 0.f) + (vB ? zoB.x * zoB.x : 0.f);
    float q1 = (vA ? zoA.y * zoA.y : 0.f) + (vB ? zoB.y * zoB.y : 0.f);
    float q2 = (vA ? zoA.z * zoA.z : 0.f) + (vB ? zoB.z * zoB.z : 0.f);
    float q3 = (vA ? zoA.w * zoA.w : 0.f) + (vB ? zoB.w * zoB.w : 0.f);
#pragma unroll
    for (int m = 1; m < 8; m <<= 1) {
        s0 += __shfl_xor(s0, m, 64); s1 += __shfl_xor(s1, m, 64);
        s2 += __shfl_xor(s2, m, 64); s3 += __shfl_xor(s3, m, 64);
        q0 += __shfl_xor(q0, m, 64); q1 += __shfl_xor(q1, m, 64);
        q2 += __shfl_xor(q2, m, 64); q3 += __shfl_xor(q3, m, 64);
    }
    if (nd == 0) {
        psum[wv][oct * 4 + 0] = s0; psum[wv][oct * 4 + 1] = s1;
        psum[wv][oct * 4 + 2] = s2; psum[wv][oct * 4 + 3] = s3;
        psq[wv][oct * 4 + 0] = q0;  psq[wv][oct * 4 + 1] = q1;
        psq[wv][oct * 4 + 2] = q2;  psq[wv][oct * 4 + 3] = q3;
    }
    __syncthreads();
    if (threadIdx.x < 32) {
        int c = threadIdx.x;
        pstat[(size_t)c * PSROW + blockIdx.x] =
            psum[0][c] + psum[1][c] + psum[2][c] + psum[3][c];
    } else if (threadIdx.x < 64) {
        int c = threadIdx.x - 32;
        pstat[(size_t)(32 + c) * PSROW + blockIdx.x] =
            psq[0][c] + psq[1][c] + psq[2][c] + psq[3][c];
    }
}

// ---------- stats reducer: 64 blocks, coalesced row sums ----------
__global__ void __launch_bounds__(256) k_statsR(const float* __restrict__ pstat, float* __restrict__ stats) {
    __shared__ float ls[4];
    int r = blockIdx.x;
    const float* row = pstat + (size_t)r * PSROW;
    float s = 0.f;
    for (int i = threadIdx.x; i < NBMLP; i += 256) s += row[i];
#pragma unroll
    for (int m = 1; m < 64; m <<= 1) s += __shfl_xor(s, m, 64);
    if ((threadIdx.x & 63) == 0) ls[threadIdx.x >> 6] = s;
    __syncthreads();
    if (threadIdx.x == 0) stats[r] = ls[0] + ls[1] + ls[2] + ls[3];
}

// ---------- BN apply + relu + eb fold, fp16 mirror only (layer-1) ----------
__global__ void k_bnh(const float* __restrict__ z, __half* __restrict__ m,
                      const float* __restrict__ stats, const float* __restrict__ g,
                      const float* __restrict__ b, const float* __restrict__ eb) {
    int t = blockIdx.x * 256 + threadIdx.x;
    if (t >= N_NODES * 8) return;
    int q = t & 7;
    float4 zv = ((const float4*)z)[t];
    float* zp = (float*)&zv;
    float ov[4];
    const float invN = 1.0f / (float)N_NODES;
#pragma unroll
    for (int i = 0; i < 4; i++) {
        int c = q * 4 + i;
        float mu = stats[c] * invN;
        float var = stats[32 + c] * invN - mu * mu;
        float sc = g[c] / sqrtf(var + BN_EPS);
        ov[i] = fmaxf((zp[i] - mu) * sc + b[c], 0.f) + eb[c];
    }
    __half2* hq = (__half2*)(m + (size_t)t * 4);
    hq[0] = __floats2half2_rn(ov[0], ov[1]);
    hq[1] = __floats2half2_rn(ov[2], ov[3]);
}

// ---------- fused mean-pool (BN2+relu inline) + head MLP: one wave per graph ----------
__global__ void __launch_bounds__(256) k_poolhead(const float* __restrict__ z, const int* __restrict__ goff,
                                                  const float* __restrict__ stats,
                                                  const float* __restrict__ bg, const float* __restrict__ bb,
                                                  const float* __restrict__ W1, const float* __restrict__ b1,
                                                  const float* __restrict__ W2, const float* __restrict__ b2,
                                                  float* __restrict__ out) {
    __shared__ float sW1[512];
    __shared__ float sb1[16], sW2[32], sb2[2];
    __shared__ float gxs[4][32];
    for (int i = threadIdx.x; i < 512; i += 256) sW1[i] = W1[i];
    if (threadIdx.x < 16) sb1[threadIdx.x] = b1[threadIdx.x];
    if (threadIdx.x < 32) sW2[threadIdx.x] = W2[threadIdx.x];
    if (threadIdx.x < 2) sb2[threadIdx.x] = b2[threadIdx.x];
    __syncthreads();
    int wid = threadIdx.x >> 6, lane = threadIdx.x & 63;
    int gi = blockIdx.x * 4 + wid;
    int s = goff[gi], e = goff[gi + 1];
    int c = lane & 31, half = lane >> 5;
    const float invN = 1.0f / (float)N_NODES;
    float mu = stats[c] * invN;
    float var = stats[32 + c] * invN - mu * mu;
    float scl = bg[c] / sqrtf(var + BN_EPS);
    float sft = bb[c] - mu * scl;
    float acc = 0.f;
    for (int n = s + half; n < e; n += 2)
        acc += fmaxf(z[(size_t)n * 32 + c] * scl + sft, 0.f);
    acc += __shfl_down(acc, 32, 64);
    float inv = 1.0f / fmaxf((float)(e - s), 1.0f);
    if (lane < 32) gxs[wid][c] = acc * inv;
    float hid = 0.f;
    if (lane < 16) {
        float a = sb1[lane];
#pragma unroll
        for (int cc = 0; cc < 32; cc++) a += gxs[wid][cc] * sW1[cc * 16 + lane];
        hid = fmaxf(a, 0.f);
    }
    float p0 = 0.f, p1 = 0.f;
    if (lane < 16) { p0 = hid * sW2[lane * 2 + 0]; p1 = hid * sW2[lane * 2 + 1]; }
#pragma unroll
    for (int m = 1; m < 16; m <<= 1) {
        p0 += __shfl_xor(p0, m, 64);
        p1 += __shfl_xor(p1, m, 64);
    }
    if (lane == 0) {
        out[(size_t)gi * 2 + 0] = p0 + sb2[0];
        out[(size_t)gi * 2 + 1] = p1 + sb2[1];
    }
}

extern "C" void kernel_launch(void* const* d_in, const int* in_sizes, int n_in,
                              void* d_out, int out_size, void* d_ws, size_t ws_size,
                              hipStream_t stream) {
    const float* x       = (const float*)d_in[0];
    const int*   ei      = (const int*)d_in[1];
    const float* eattr   = (const float*)d_in[2];
    const int*   batch   = (const int*)d_in[3];
    const float* node_w  = (const float*)d_in[4];
    const float* node_b  = (const float*)d_in[5];
    const float* edge_w  = (const float*)d_in[6];
    const float* edge_b  = (const float*)d_in[7];
    const float* conv_w1 = (const float*)d_in[8];
    const float* conv_b1 = (const float*)d_in[9];
    const float* conv_w2 = (const float*)d_in[10];
    const float* conv_b2 = (const float*)d_in[11];
    const float* bn_g    = (const float*)d_in[12];
    const float* bn_b    = (const float*)d_in[13];
    const float* lin1_w  = (const float*)d_in[14];
    const float* lin1_b  = (const float*)d_in[15];
    const float* lin2_w  = (const float*)d_in[16];
    const float* lin2_b  = (const float*)d_in[17];
    float* out = (float*)d_out;

    uint2*  buf1    = (uint2*)d_ws;                         // 25.6 MB (8-B quantized records)
    uint2*  packed  = buf1 + N_EDGES;                       // 25.6 MB (CSR-ordered 8-B records)
    float*  h       = (float*)(packed + N_EDGES);           // 12.8 MB (h0, then zin2/z2)
    float*  agg     = h + (size_t)N_NODES * 32;             // 12.8 MB (zin1/z1)
    __half* m16     = (__half*)(agg + (size_t)N_NODES * 32);// 6.4 MB (h0+eb mirror, then BN1+eb mirror)
    unsigned char* key = (unsigned char*)(m16 + (size_t)N_NODES * 32); // 3.2 MB
    int*    cmat    = (int*)(key + N_EDGES);                // LALLOC ints
    float*  stats   = (float*)(cmat + LALLOC);              // 128 floats
    int*    t1      = (int*)(stats + 128);                  // 2560
    int*    offs    = t1 + 2560;                            // NPAD2+1
    int*    goff    = offs + NPAD2 + 1;                     // N_GRAPHS+1
    float*  pstat   = (float*)(goff + N_GRAPHS + 1);        // 64*PSROW
    float*  w1tp    = pstat + 64 * PSROW;                   // 2*80*32
    float*  b1p     = w1tp + 2 * HPAD * 32;                 // 2*80
    float*  w2p     = b1p + 2 * HPAD;                       // 2*80*32

    int nb_vec = (N_NODES * 8 + 255) / 256;

    // fused front: ksA (+pad zero) || encoder || weight prep || goff — no memset needed
    k_front<<<NBLKA + NB_ENC + 1 + NB_GOFF, 256, 0, stream>>>(
        ei, cmat, x, node_w, node_b, edge_b, h, m16,
        conv_w1, conv_b1, conv_w2, w1tp, b1p, w2p, batch, goff);

    ks1<<<NS1, 256, 0, stream>>>(cmat, t1);
    ks2<NS1, 10><<<1, 256, 0, stream>>>(t1);
    ks3<<<NS1, 256, 0, stream>>>(cmat, t1);
    ksB<<<NBLKA, 256, 0, stream>>>(ei, eattr, cmat, buf1, key);
    ksC<<<NBKT, 1024, 0, stream>>>(cmat, buf1, key, packed, offs);

    // layer 1
    k_agg<false><<<N_NODES * 32 / 256, 256, 0, stream>>>(packed, offs, edge_w,
                                                         m16, h, stats, bn_g, bn_b, agg);
    k_mlp<<<NBMLP, 256, 0, stream>>>(agg, w1tp, b1p, w2p, conv_b2, pstat);
    k_statsR<<<64, 256, 0, stream>>>(pstat, stats);
    k_bnh<<<nb_vec, 256, 0, stream>>>(agg, m16, stats, bn_g, bn_b, edge_b);
    // layer 2
    k_agg<true><<<N_NODES * 32 / 256, 256, 0, stream>>>(packed, offs, edge_w,
                                                        m16, agg, stats, bn_g, bn_b, h);
    k_mlp<<<NBMLP, 256, 0, stream>>>(h, w1tp + HPAD * 32, b1p + HPAD,
                                     w2p + HPAD * 32, conv_b2 + 32, pstat);
    k_statsR<<<64, 256, 0, stream>>>(pstat, stats + 64);
    k_poolhead<<<N_GRAPHS / 4, 256, 0, stream>>>(h, goff, stats + 64, bn_g + 32, bn_b + 32,
                                                 lin1_w, lin1_b, lin2_w, lin2_b, out);
}

// Round 14
// 416.010 us; speedup vs baseline: 1.1044x; 1.0124x over previous
//
#include <hip/hip_runtime.h>
#include <hip/hip_fp16.h>

#define N_NODES 100000
#define N_EDGES 3200000
#define N_GRAPHS 5000
#define BN_EPS 1e-5f
#define HPAD 80        // hidden 75 padded to 80
#define CHUNK 2048     // edges per bucket-sort block
#define NBLKA 1563     // ceil(N_EDGES / CHUNK)
#define NBKT 392       // buckets of 256 nodes (dst >> 8)
#define NPAD2 (NBKT * 256)     // 100352
#define NBLK_TOT (NBKT * NBLKA)  // 612696
#define NS1 2394       // ceil(NBLK_TOT / 256)
#define LALLOC (NS1 * 256)
#define W1S 36         // sW1 row stride: 2-way bank alias only (free)
#define NB_ENC 391     // encode blocks in k_front
#define NB_GOFF 20     // goff blocks in k_front
#define NBMLP 1563     // k_mlp grid: 2 nodes/thread, 64 nodes/block
#define PSROW 1568     // pstat row stride (padded)
#define ISC (1.0f / 32767.0f)   // attr dequant scale (folded into eW in k_agg)

// ---------- fused front: bucket histogram (+pad zero) + node encoder + weight prep + goff ----------
__global__ void __launch_bounds__(256) k_front(const int* __restrict__ ei, int* __restrict__ cmat,
                                               const float* __restrict__ x, const float* __restrict__ nW,
                                               const float* __restrict__ nb, const float* __restrict__ eb,
                                               float* __restrict__ h, __half* __restrict__ h16,
                                               const float* __restrict__ W1, const float* __restrict__ b1,
                                               const float* __restrict__ W2,
                                               float* __restrict__ w1tp, float* __restrict__ b1p,
                                               float* __restrict__ w2p,
                                               const int* __restrict__ batch, int* __restrict__ goff) {
    int bid = blockIdx.x;
    if (bid < NBLKA) {
        __shared__ int lh[NBKT];
        if (bid == 0) {
            for (int i = threadIdx.x; i < LALLOC - NBLK_TOT; i += 256)
                cmat[NBLK_TOT + i] = 0;
        }
        for (int i = threadIdx.x; i < NBKT; i += 256) lh[i] = 0;
        __syncthreads();
        int b0 = bid * CHUNK;
        for (int i = threadIdx.x; i < CHUNK; i += 256) {
            int e = b0 + i;
            if (e < N_EDGES) atomicAdd(&lh[ei[N_EDGES + e] >> 8], 1);
        }
        __syncthreads();
        for (int i = threadIdx.x; i < NBKT; i += 256)
            cmat[i * NBLKA + bid] = lh[i];
    } else if (bid < NBLKA + NB_ENC) {
        __shared__ float sW[448];
        __shared__ float sb[32];
        __shared__ float seb[32];
        for (int i = threadIdx.x; i < 448; i += 256) sW[i] = nW[i];
        if (threadIdx.x < 32) { sb[threadIdx.x] = nb[threadIdx.x]; seb[threadIdx.x] = eb[threadIdx.x]; }
        __syncthreads();
        int n = (bid - NBLKA) * 256 + threadIdx.x;
        if (n >= N_NODES) return;
        float xi[14];
#pragma unroll
        for (int k = 0; k < 14; k++) xi[k] = x[n * 14 + k];
        float4* hp = (float4*)(h + (size_t)n * 32);
        __half2* hq = (__half2*)(h16 + (size_t)n * 32);
#pragma unroll
        for (int q = 0; q < 8; q++) {
            float4 acc;
            float* ap = (float*)&acc;
#pragma unroll
            for (int i = 0; i < 4; i++) {
                int c = q * 4 + i;
                float a = sb[c];
#pragma unroll
                for (int k = 0; k < 14; k++) a += xi[k] * sW[k * 32 + c];
                ap[i] = a;
            }
            hp[q] = acc;
            int c = q * 4;
            hq[q * 2 + 0] = __floats2half2_rn(acc.x + seb[c + 0], acc.y + seb[c + 1]);
            hq[q * 2 + 1] = __floats2half2_rn(acc.z + seb[c + 2], acc.w + seb[c + 3]);
        }
    } else if (bid == NBLKA + NB_ENC) {
        for (int i = threadIdx.x; i < 2 * HPAD * 32 + 2 * HPAD; i += 256) {
            if (i < 2 * HPAD * 32) {
                int l = i / (HPAD * 32), r = i % (HPAD * 32);
                int j = r / 32, c = r % 32;
                w1tp[i] = (j < 75) ? W1[l * 2400 + c * 75 + j] : 0.f;
                w2p[i]  = (j < 75) ? W2[l * 2400 + j * 32 + c] : 0.f;
            } else {
                int k = i - 2 * HPAD * 32;
                int l = k / HPAD, j = k % HPAD;
                b1p[k] = (j < 75) ? b1[l * 75 + j] : 0.f;
            }
        }
    } else {
        int g = (bid - NBLKA - NB_ENC - 1) * 256 + threadIdx.x;
        if (g > N_GRAPHS) return;
        int lo = 0, hi = N_NODES;
        while (lo < hi) {
            int mid = (lo + hi) >> 1;
            if (batch[mid] < g) lo = mid + 1; else hi = mid;
        }
        goff[g] = lo;
    }
}

// ---------- 3-kernel exclusive scan of cmat ----------
__global__ void ks1(const int* __restrict__ a, int* __restrict__ bs) {
    __shared__ int s[256];
    int i = blockIdx.x * 256 + threadIdx.x;
    s[threadIdx.x] = a[i];
    __syncthreads();
    for (int o = 128; o > 0; o >>= 1) {
        if (threadIdx.x < o) s[threadIdx.x] += s[threadIdx.x + o];
        __syncthreads();
    }
    if (threadIdx.x == 0) bs[blockIdx.x] = s[0];
}

template<int NSX, int VPTX>
__global__ void ks2(int* __restrict__ bs) {
    __shared__ int s[256];
    int t = threadIdx.x;
    int v[VPTX];
    int base = t * VPTX, sum = 0;
#pragma unroll
    for (int k = 0; k < VPTX; k++) {
        int idx = base + k;
        int x = (idx < NSX) ? bs[idx] : 0;
        v[k] = sum; sum += x;
    }
    s[t] = sum;
    __syncthreads();
    for (int o = 1; o < 256; o <<= 1) {
        int add = (t >= o) ? s[t - o] : 0;
        __syncthreads();
        s[t] += add;
        __syncthreads();
    }
    int excl = (t == 0) ? 0 : s[t - 1];
#pragma unroll
    for (int k = 0; k < VPTX; k++) {
        int idx = base + k;
        if (idx < NSX) bs[idx] = excl + v[k];
    }
}

__global__ void ks3(int* __restrict__ a, const int* __restrict__ bs) {
    __shared__ int s[256];
    int t = threadIdx.x, i = blockIdx.x * 256 + t;
    int v = a[i];
    s[t] = v;
    __syncthreads();
    for (int o = 1; o < 256; o <<= 1) {
        int add = (t >= o) ? s[t - o] : 0;
        __syncthreads();
        s[t] += add;
        __syncthreads();
    }
    a[i] = s[t] - v + bs[blockIdx.x];
}

// ---------- phase B: counting sort in LDS, 8-byte quantized records + key/dl bytes ----------
__global__ void __launch_bounds__(256) ksB(const int* __restrict__ ei, const float* __restrict__ ea,
                                           const int* __restrict__ cmat, uint2* __restrict__ buf1,
                                           unsigned char* __restrict__ key) {
    __shared__ uint2 rec[CHUNK];           // 16 KB
    __shared__ unsigned short sbkt[CHUNK]; // 4 KB
    __shared__ unsigned char sdl[CHUNK];   // 2 KB
    __shared__ int lh[NBKT];
    __shared__ int lex[NBKT];
    __shared__ int gb[NBKT];
    __shared__ int sc[256];
    int t = threadIdx.x;
    int b0 = blockIdx.x * CHUNK;
    int nval = min(CHUNK, N_EDGES - b0);
    for (int i = t; i < NBKT; i += 256) lh[i] = 0;
    __syncthreads();
    for (int i = t; i < nval; i += 256)
        atomicAdd(&lh[ei[N_EDGES + b0 + i] >> 8], 1);
    __syncthreads();
    int x0 = (t * 2 < NBKT) ? lh[t * 2] : 0;
    int x1 = (t * 2 + 1 < NBKT) ? lh[t * 2 + 1] : 0;
    int v0 = 0, v1 = x0, run = x0 + x1;
    sc[t] = run;
    __syncthreads();
    for (int o = 1; o < 256; o <<= 1) {
        int add = (t >= o) ? sc[t - o] : 0;
        __syncthreads();
        sc[t] += add;
        __syncthreads();
    }
    int excl = (t == 0) ? 0 : sc[t - 1];
    if (t * 2 < NBKT) {
        int base = excl + v0;
        lex[t * 2] = base; lh[t * 2] = base;
        gb[t * 2] = cmat[(t * 2) * NBLKA + blockIdx.x];
    }
    if (t * 2 + 1 < NBKT) {
        int base = excl + v1;
        lex[t * 2 + 1] = base; lh[t * 2 + 1] = base;
        gb[t * 2 + 1] = cmat[(t * 2 + 1) * NBLKA + blockIdx.x];
    }
    __syncthreads();
    for (int i = t; i < nval; i += 256) {
        int e = b0 + i;
        int src = ei[e], dst = ei[N_EDGES + e];
        float a0 = ea[(size_t)e * 3 + 0], a1 = ea[(size_t)e * 3 + 1], a2 = ea[(size_t)e * 3 + 2];
        unsigned q0 = (unsigned)(int)(a0 * 32767.f + 0.5f);
        unsigned q1 = (unsigned)(int)(a1 * 32767.f + 0.5f);
        unsigned q2 = (unsigned)(int)(a2 * 32767.f + 0.5f);
        int bkt = dst >> 8;
        int r = atomicAdd(&lh[bkt], 1);
        rec[r] = make_uint2((unsigned)src | (q0 << 17), q1 | (q2 << 15));
        sbkt[r] = (unsigned short)bkt;
        sdl[r] = (unsigned char)(dst & 255);
    }
    __syncthreads();
    for (int p = t; p < nval; p += 256) {
        int bkt = sbkt[p];
        int gp = gb[bkt] + (p - lex[bkt]);
        buf1[gp] = rec[p];
        key[gp] = sdl[p];
    }
}

// ---------- phase C: per-256-node-bucket exact CSR; pure reorder of 8B records ----------
__global__ void __launch_bounds__(1024) ksC(const int* __restrict__ cmat, const uint2* __restrict__ buf1,
                                            const unsigned char* __restrict__ key,
                                            uint2* __restrict__ packed, int* __restrict__ offs) {
    __shared__ int cnt[256];
    __shared__ int sc2[256];
    __shared__ int excl[256];
    int g = blockIdx.x, t = threadIdx.x;
    int bb = cmat[g * NBLKA];
    int be = (g == NBKT - 1) ? N_EDGES : cmat[(g + 1) * NBLKA];
    if (t < 256) cnt[t] = 0;
    __syncthreads();
    for (int j = bb + t; j < be; j += 1024) atomicAdd(&cnt[key[j]], 1);
    __syncthreads();
    if (t < 256) sc2[t] = cnt[t];
    __syncthreads();
    for (int o = 1; o < 256; o <<= 1) {
        int add = 0;
        if (t < 256 && t >= o) add = sc2[t - o];
        __syncthreads();
        if (t < 256) sc2[t] += add;
        __syncthreads();
    }
    if (t < 256) {
        excl[t] = sc2[t] - cnt[t];
        offs[(g << 8) + t] = bb + excl[t];
        cnt[t] = 0;
    }
    if (g == NBKT - 1 && t == 0) offs[NPAD2] = N_EDGES;
    __syncthreads();
    for (int j = bb + t; j < be; j += 1024) {
        uint2 r = buf1[j];
        int dl = key[j];
        int rank = atomicAdd(&cnt[dl], 1);
        packed[bb + excl[dl] + rank] = r;
    }
}

// ---------- pull aggregation: 16 threads/node (8 channels each), 8B records, inline dequant ----------
// Each edge shared by 4 threads (was 8): ~15% fewer per-edge VALU+VMEM issues; float4 h16 gathers.
// BN=true applies relu(BN1(z)) to self-term inline
template<bool BN>
__global__ void __launch_bounds__(256) k_agg(const uint2* __restrict__ packed,
                                             const int* __restrict__ offs,
                                             const float* __restrict__ eW,
                                             const __half* __restrict__ h16,
                                             const float* __restrict__ hs,
                                             const float* __restrict__ stats,
                                             const float* __restrict__ bng, const float* __restrict__ bnb,
                                             float* __restrict__ zin) {
    int t = blockIdx.x * 256 + threadIdx.x;   // N_NODES*16 exact
    int n = t >> 4, s = t & 15;
    int q = s & 3, part = s >> 2;             // q: 8-channel slice; part: edge quarter
    int c0 = q * 8;
    float w0[8], w1[8], w2[8];
#pragma unroll
    for (int i = 0; i < 8; i++) {
        w0[i] = eW[c0 + i] * ISC;        // dequant scale folded into weights
        w1[i] = eW[32 + c0 + i] * ISC;
        w2[i] = eW[64 + c0 + i] * ISC;
    }
    int beg = offs[n], end = offs[n + 1];
    float acc0[8] = {0.f, 0.f, 0.f, 0.f, 0.f, 0.f, 0.f, 0.f};
    float acc1[8] = {0.f, 0.f, 0.f, 0.f, 0.f, 0.f, 0.f, 0.f};
    int j = beg + part;
    for (; j + 4 < end; j += 8) {
        uint2 pa = packed[j];
        uint2 pb = packed[j + 4];
        unsigned offa = ((pa.x & 0x1FFFFu) << 5) + (unsigned)c0;
        unsigned offb = ((pb.x & 0x1FFFFu) << 5) + (unsigned)c0;
        float4 ra = *(const float4*)(h16 + offa);   // 8 halves
        float4 rb = *(const float4*)(h16 + offb);
        float aq0 = (float)(pa.x >> 17), aq1 = (float)(pa.y & 0x7FFFu), aq2 = (float)(pa.y >> 15);
        float bq0 = (float)(pb.x >> 17), bq1 = (float)(pb.y & 0x7FFFu), bq2 = (float)(pb.y >> 15);
        float2 a01 = __half22float2(*(__half2*)&ra.x);
        float2 a23 = __half22float2(*(__half2*)&ra.y);
        float2 a45 = __half22float2(*(__half2*)&ra.z);
        float2 a67 = __half22float2(*(__half2*)&ra.w);
        float2 b01 = __half22float2(*(__half2*)&rb.x);
        float2 b23 = __half22float2(*(__half2*)&rb.y);
        float2 b45 = __half22float2(*(__half2*)&rb.z);
        float2 b67 = __half22float2(*(__half2*)&rb.w);
        float ha8[8] = {a01.x, a01.y, a23.x, a23.y, a45.x, a45.y, a67.x, a67.y};
        float hb8[8] = {b01.x, b01.y, b23.x, b23.y, b45.x, b45.y, b67.x, b67.y};
#pragma unroll
        for (int i = 0; i < 8; i++) {
            acc0[i] += fmaxf(ha8[i] + aq0 * w0[i] + aq1 * w1[i] + aq2 * w2[i], 0.f);
            acc1[i] += fmaxf(hb8[i] + bq0 * w0[i] + bq1 * w1[i] + bq2 * w2[i], 0.f);
        }
    }
    if (j < end) {
        uint2 p = packed[j];
        unsigned offp = ((p.x & 0x1FFFFu) << 5) + (unsigned)c0;
        float4 r = *(const float4*)(h16 + offp);
        float pq0 = (float)(p.x >> 17), pq1 = (float)(p.y & 0x7FFFu), pq2 = (float)(p.y >> 15);
        float2 a01 = __half22float2(*(__half2*)&r.x);
        float2 a23 = __half22float2(*(__half2*)&r.y);
        float2 a45 = __half22float2(*(__half2*)&r.z);
        float2 a67 = __half22float2(*(__half2*)&r.w);
        float hp8[8] = {a01.x, a01.y, a23.x, a23.y, a45.x, a45.y, a67.x, a67.y};
#pragma unroll
        for (int i = 0; i < 8; i++)
            acc0[i] += fmaxf(hp8[i] + pq0 * w0[i] + pq1 * w1[i] + pq2 * w2[i], 0.f);
    }
    float acc[8];
#pragma unroll
    for (int i = 0; i < 8; i++) {
        acc[i] = acc0[i] + acc1[i];
        acc[i] += __shfl_xor(acc[i], 4, 64);   // combine parts (lane bits 2-3)
        acc[i] += __shfl_xor(acc[i], 8, 64);
    }
    if (part == 0) {
        float4 hq0 = *(const float4*)(hs + (size_t)n * 32 + c0);
        float4 hq1 = *(const float4*)(hs + (size_t)n * 32 + c0 + 4);
        float hp[8] = {hq0.x, hq0.y, hq0.z, hq0.w, hq1.x, hq1.y, hq1.z, hq1.w};
        float sv[8];
        if (BN) {
            const float invN = 1.0f / (float)N_NODES;
#pragma unroll
            for (int i = 0; i < 8; i++) {
                int c = c0 + i;
                float mu = stats[c] * invN;
                float var = stats[32 + c] * invN - mu * mu;
                float scl = bng[c] / sqrtf(var + BN_EPS);
                float sft = bnb[c] - mu * scl;
                sv[i] = fmaxf(hp[i] * scl + sft, 0.f);
            }
        } else {
#pragma unroll
            for (int i = 0; i < 8; i++) sv[i] = hp[i];
        }
        *(float4*)(zin + (size_t)n * 32 + c0) =
            make_float4(acc[0] + sv[0], acc[1] + sv[1], acc[2] + sv[2], acc[3] + sv[3]);
        *(float4*)(zin + (size_t)n * 32 + c0 + 4) =
            make_float4(acc[4] + sv[4], acc[5] + sv[5], acc[6] + sv[6], acc[7] + sv[7]);
    }
}

// ---------- fused MLP, 2 nodes/thread, named float4 regs + per-block BN partial stats ----------
__global__ void __launch_bounds__(256, 2) k_mlp(float* __restrict__ zio,
                                                const float* __restrict__ W1, const float* __restrict__ B1,
                                                const float* __restrict__ W2, const float* __restrict__ b2,
                                                float* __restrict__ pstat) {
    __shared__ float sW1[HPAD * W1S];  // 11.25 KB
    __shared__ float sW2[2560];        // 10 KB
    __shared__ float sB1[80];
    __shared__ float sb2[32];
    __shared__ float hidL[64 * 84];    // 21 KB
    __shared__ float psum[4][32];
    __shared__ float psq[4][32];
    for (int i = threadIdx.x; i < 2560; i += 256) {
        int j = i >> 5, c = i & 31;
        sW1[j * W1S + c] = W1[i];
        sW2[i] = W2[i];
    }
    if (threadIdx.x < 80) sB1[threadIdx.x] = B1[threadIdx.x];
    if (threadIdx.x < 32) sb2[threadIdx.x] = b2[threadIdx.x];
    __syncthreads();
    unsigned lane = threadIdx.x & 63;
    unsigned wv = threadIdx.x >> 6;
    unsigned oct = lane >> 3;
    unsigned nd = lane & 7;
    unsigned nA = blockIdx.x * 64 + wv * 16 + nd;
    unsigned nB = nA + 8;
    bool vA = nA < N_NODES, vB = nB < N_NODES;
    unsigned nAc = vA ? nA : (N_NODES - 1);
    unsigned nBc = vB ? nB : (N_NODES - 1);
    const float4* apA = (const float4*)(zio + (size_t)nAc * 32);
    const float4* apB = (const float4*)(zio + (size_t)nBc * 32);
    float4 zA0 = apA[0], zA1 = apA[1], zA2 = apA[2], zA3 = apA[3];
    float4 zA4 = apA[4], zA5 = apA[5], zA6 = apA[6], zA7 = apA[7];
    float4 zB0 = apB[0], zB1 = apB[1], zB2 = apB[2], zB3 = apB[3];
    float4 zB4 = apB[4], zB5 = apB[5], zB6 = apB[6], zB7 = apB[7];
    float* hrowA = &hidL[(wv * 16 + nd) * 84];
    float* hrowB = &hidL[(wv * 16 + 8 + nd) * 84];
#pragma unroll
    for (int i = 0; i < 10; i++) {
        int j = (int)oct * 10 + i;
        const float4* wp = (const float4*)(sW1 + j * W1S);
        float a0 = 0.f, a1 = 0.f, a2 = 0.f, a3 = 0.f;
        float b0 = 0.f, b1v = 0.f, b2v = 0.f, b3 = 0.f;
#define MLP_STEP(Q, ZA, ZB)                                   \
        { float4 w4 = wp[Q];                                  \
          a0 += ZA.x * w4.x; a1 += ZA.y * w4.y;               \
          a2 += ZA.z * w4.z; a3 += ZA.w * w4.w;               \
          b0 += ZB.x * w4.x; b1v += ZB.y * w4.y;              \
          b2v += ZB.z * w4.z; b3 += ZB.w * w4.w; }
        MLP_STEP(0, zA0, zB0)
        MLP_STEP(1, zA1, zB1)
        MLP_STEP(2, zA2, zB2)
        MLP_STEP(3, zA3, zB3)
        MLP_STEP(4, zA4, zB4)
        MLP_STEP(5, zA5, zB5)
        MLP_STEP(6, zA6, zB6)
        MLP_STEP(7, zA7, zB7)
#undef MLP_STEP
        float bias = sB1[j];
        hrowA[oct * 10 + i] = fmaxf(bias + ((a0 + a1) + (a2 + a3)), 0.f);
        hrowB[oct * 10 + i] = fmaxf(bias + ((b0 + b1v) + (b2v + b3)), 0.f);
    }
    float4 zoA = *(const float4*)(sb2 + oct * 4);
    float4 zoB = zoA;
    const float4* hvA4 = (const float4*)hrowA;
    const float4* hvB4 = (const float4*)hrowB;
#pragma unroll
    for (int k = 0; k < 20; k++) {
        float4 ha = hvA4[k];
        float4 hb = hvB4[k];
        const float* wr = sW2 + (k * 4) * 32 + oct * 4;
        float4 wa = *(const float4*)(wr);
        float4 wb = *(const float4*)(wr + 32);
        float4 wc = *(const float4*)(wr + 64);
        float4 wd = *(const float4*)(wr + 96);
        zoA.x += ha.x * wa.x + ha.y * wb.x + ha.z * wc.x + ha.w * wd.x;
        zoA.y += ha.x * wa.y + ha.y * wb.y + ha.z * wc.y + ha.w * wd.y;
        zoA.z += ha.x * wa.z + ha.y * wb.z + ha.z * wc.z + ha.w * wd.z;
        zoA.w += ha.x * wa.w + ha.y * wb.w + ha.z * wc.w + ha.w * wd.w;
        zoB.x += hb.x * wa.x + hb.y * wb.x + hb.z * wc.x + hb.w * wd.x;
        zoB.y += hb.x * wa.y + hb.y * wb.y + hb.z * wc.y + hb.w * wd.y;
        zoB.z += hb.x * wa.z + hb.y * wb.z + hb.z * wc.z + hb.w * wd.z;
        zoB.w += hb.x * wa.w + hb.y * wb.w + hb.z * wc.w + hb.w * wd.w;
    }
    if (vA) *(float4*)(zio + (size_t)nA * 32 + oct * 4) = zoA;
    if (vB) *(float4*)(zio + (size_t)nB * 32 + oct * 4) = zoB;
    float s0 = (vA ? zoA.x : 0.f) + (vB ? zoB.x : 0.f);
    float s1 = (vA ? zoA.y : 0.f) + (vB ? zoB.y : 0.f);
    float s2 = (vA ? zoA.z : 0.f) + (vB ? zoB.z : 0.f);
    float s3 = (vA ? zoA.w : 0.f) + (vB ? zoB.w : 0.f);
    float q0 = (vA ? zoA.x * zoA.x : 0.f) + (vB ? zoB.x * zoB.x : 0.f);
    float q1 = (vA ? zoA.y * zoA.y : 0.f) + (vB ? zoB.y * zoB.y : 0.f);
    float q2 = (vA ? zoA.z * zoA.z : 0.f) + (vB ? zoB.z * zoB.z : 0.f);
    float q3 = (vA ? zoA.w * zoA.w : 0.f) + (vB ? zoB.w * zoB.w : 0.f);
#pragma unroll
    for (int m = 1; m < 8; m <<= 1) {
        s0 += __shfl_xor(s0, m, 64); s1 += __shfl_xor(s1, m, 64);
        s2 += __shfl_xor(s2, m, 64); s3 += __shfl_xor(s3, m, 64);
        q0 += __shfl_xor(q0, m, 64); q1 += __shfl_xor(q1, m, 64);
        q2 += __shfl_xor(q2, m, 64); q3 += __shfl_xor(q3, m, 64);
    }
    if (nd == 0) {
        psum[wv][oct * 4 + 0] = s0; psum[wv][oct * 4 + 1] = s1;
        psum[wv][oct * 4 + 2] = s2; psum[wv][oct * 4 + 3] = s3;
        psq[wv][oct * 4 + 0] = q0;  psq[wv][oct * 4 + 1] = q1;
        psq[wv][oct * 4 + 2] = q2;  psq[wv][oct * 4 + 3] = q3;
    }
    __syncthreads();
    if (threadIdx.x < 32) {
        int c = threadIdx.x;
        pstat[(size_t)c * PSROW + blockIdx.x] =
            psum[0][c] + psum[1][c] + psum[2][c] + psum[3][c];
    } else if (threadIdx.x < 64) {
        int c = threadIdx.x - 32;
        pstat[(size_t)(32 + c) * PSROW + blockIdx.x] =
            psq[0][c] + psq[1][c] + psq[2][c] + psq[3][c];
    }
}

// ---------- stats reducer: 64 blocks, coalesced row sums ----------
__global__ void __launch_bounds__(256) k_statsR(const float* __restrict__ pstat, float* __restrict__ stats) {
    __shared__ float ls[4];
    int r = blockIdx.x;
    const float* row = pstat + (size_t)r * PSROW;
    float s = 0.f;
    for (int i = threadIdx.x; i < NBMLP; i += 256) s += row[i];
#pragma unroll
    for (int m = 1; m < 64; m <<= 1) s += __shfl_xor(s, m, 64);
    if ((threadIdx.x & 63) == 0) ls[threadIdx.x >> 6] = s;
    __syncthreads();
    if (threadIdx.x == 0) stats[r] = ls[0] + ls[1] + ls[2] + ls[3];
}

// ---------- BN apply + relu + eb fold, fp16 mirror only (layer-1) ----------
__global__ void k_bnh(const float* __restrict__ z, __half* __restrict__ m,
                      const float* __restrict__ stats, const float* __restrict__ g,
                      const float* __restrict__ b, const float* __restrict__ eb) {
    int t = blockIdx.x * 256 + threadIdx.x;
    if (t >= N_NODES * 8) return;
    int q = t & 7;
    float4 zv = ((const float4*)z)[t];
    float* zp = (float*)&zv;
    float ov[4];
    const float invN = 1.0f / (float)N_NODES;
#pragma unroll
    for (int i = 0; i < 4; i++) {
        int c = q * 4 + i;
        float mu = stats[c] * invN;
        float var = stats[32 + c] * invN - mu * mu;
        float sc = g[c] / sqrtf(var + BN_EPS);
        ov[i] = fmaxf((zp[i] - mu) * sc + b[c], 0.f) + eb[c];
    }
    __half2* hq = (__half2*)(m + (size_t)t * 4);
    hq[0] = __floats2half2_rn(ov[0], ov[1]);
    hq[1] = __floats2half2_rn(ov[2], ov[3]);
}

// ---------- fused mean-pool (BN2+relu inline) + head MLP: one wave per graph ----------
__global__ void __launch_bounds__(256) k_poolhead(const float* __restrict__ z, const int* __restrict__ goff,
                                                  const float* __restrict__ stats,
                                                  const float* __restrict__ bg, const float* __restrict__ bb,
                                                  const float* __restrict__ W1, const float* __restrict__ b1,
                                                  const float* __restrict__ W2, const float* __restrict__ b2,
                                                  float* __restrict__ out) {
    __shared__ float sW1[512];
    __shared__ float sb1[16], sW2[32], sb2[2];
    __shared__ float gxs[4][32];
    for (int i = threadIdx.x; i < 512; i += 256) sW1[i] = W1[i];
    if (threadIdx.x < 16) sb1[threadIdx.x] = b1[threadIdx.x];
    if (threadIdx.x < 32) sW2[threadIdx.x] = W2[threadIdx.x];
    if (threadIdx.x < 2) sb2[threadIdx.x] = b2[threadIdx.x];
    __syncthreads();
    int wid = threadIdx.x >> 6, lane = threadIdx.x & 63;
    int gi = blockIdx.x * 4 + wid;
    int s = goff[gi], e = goff[gi + 1];
    int c = lane & 31, half = lane >> 5;
    const float invN = 1.0f / (float)N_NODES;
    float mu = stats[c] * invN;
    float var = stats[32 + c] * invN - mu * mu;
    float scl = bg[c] / sqrtf(var + BN_EPS);
    float sft = bb[c] - mu * scl;
    float acc = 0.f;
    for (int n = s + half; n < e; n += 2)
        acc += fmaxf(z[(size_t)n * 32 + c] * scl + sft, 0.f);
    acc += __shfl_down(acc, 32, 64);
    float inv = 1.0f / fmaxf((float)(e - s), 1.0f);
    if (lane < 32) gxs[wid][c] = acc * inv;
    float hid = 0.f;
    if (lane < 16) {
        float a = sb1[lane];
#pragma unroll
        for (int cc = 0; cc < 32; cc++) a += gxs[wid][cc] * sW1[cc * 16 + lane];
        hid = fmaxf(a, 0.f);
    }
    float p0 = 0.f, p1 = 0.f;
    if (lane < 16) { p0 = hid * sW2[lane * 2 + 0]; p1 = hid * sW2[lane * 2 + 1]; }
#pragma unroll
    for (int m = 1; m < 16; m <<= 1) {
        p0 += __shfl_xor(p0, m, 64);
        p1 += __shfl_xor(p1, m, 64);
    }
    if (lane == 0) {
        out[(size_t)gi * 2 + 0] = p0 + sb2[0];
        out[(size_t)gi * 2 + 1] = p1 + sb2[1];
    }
}

extern "C" void kernel_launch(void* const* d_in, const int* in_sizes, int n_in,
                              void* d_out, int out_size, void* d_ws, size_t ws_size,
                              hipStream_t stream) {
    const float* x       = (const float*)d_in[0];
    const int*   ei      = (const int*)d_in[1];
    const float* eattr   = (const float*)d_in[2];
    const int*   batch   = (const int*)d_in[3];
    const float* node_w  = (const float*)d_in[4];
    const float* node_b  = (const float*)d_in[5];
    const float* edge_w  = (const float*)d_in[6];
    const float* edge_b  = (const float*)d_in[7];
    const float* conv_w1 = (const float*)d_in[8];
    const float* conv_b1 = (const float*)d_in[9];
    const float* conv_w2 = (const float*)d_in[10];
    const float* conv_b2 = (const float*)d_in[11];
    const float* bn_g    = (const float*)d_in[12];
    const float* bn_b    = (const float*)d_in[13];
    const float* lin1_w  = (const float*)d_in[14];
    const float* lin1_b  = (const float*)d_in[15];
    const float* lin2_w  = (const float*)d_in[16];
    const float* lin2_b  = (const float*)d_in[17];
    float* out = (float*)d_out;

    uint2*  buf1    = (uint2*)d_ws;                         // 25.6 MB (8-B quantized records)
    uint2*  packed  = buf1 + N_EDGES;                       // 25.6 MB (CSR-ordered 8-B records)
    float*  h       = (float*)(packed + N_EDGES);           // 12.8 MB (h0, then zin2/z2)
    float*  agg     = h + (size_t)N_NODES * 32;             // 12.8 MB (zin1/z1)
    __half* m16     = (__half*)(agg + (size_t)N_NODES * 32);// 6.4 MB (h0+eb mirror, then BN1+eb mirror)
    unsigned char* key = (unsigned char*)(m16 + (size_t)N_NODES * 32); // 3.2 MB
    int*    cmat    = (int*)(key + N_EDGES);                // LALLOC ints
    float*  stats   = (float*)(cmat + LALLOC);              // 128 floats
    int*    t1      = (int*)(stats + 128);                  // 2560
    int*    offs    = t1 + 2560;                            // NPAD2+1
    int*    goff    = offs + NPAD2 + 1;                     // N_GRAPHS+1
    float*  pstat   = (float*)(goff + N_GRAPHS + 1);        // 64*PSROW
    float*  w1tp    = pstat + 64 * PSROW;                   // 2*80*32
    float*  b1p     = w1tp + 2 * HPAD * 32;                 // 2*80
    float*  w2p     = b1p + 2 * HPAD;                       // 2*80*32

    int nb_vec = (N_NODES * 8 + 255) / 256;

    k_front<<<NBLKA + NB_ENC + 1 + NB_GOFF, 256, 0, stream>>>(
        ei, cmat, x, node_w, node_b, edge_b, h, m16,
        conv_w1, conv_b1, conv_w2, w1tp, b1p, w2p, batch, goff);

    ks1<<<NS1, 256, 0, stream>>>(cmat, t1);
    ks2<NS1, 10><<<1, 256, 0, stream>>>(t1);
    ks3<<<NS1, 256, 0, stream>>>(cmat, t1);
    ksB<<<NBLKA, 256, 0, stream>>>(ei, eattr, cmat, buf1, key);
    ksC<<<NBKT, 1024, 0, stream>>>(cmat, buf1, key, packed, offs);

    // layer 1
    k_agg<false><<<N_NODES * 16 / 256, 256, 0, stream>>>(packed, offs, edge_w,
                                                         m16, h, stats, bn_g, bn_b, agg);
    k_mlp<<<NBMLP, 256, 0, stream>>>(agg, w1tp, b1p, w2p, conv_b2, pstat);
    k_statsR<<<64, 256, 0, stream>>>(pstat, stats);
    k_bnh<<<nb_vec, 256, 0, stream>>>(agg, m16, stats, bn_g, bn_b, edge_b);
    // layer 2
    k_agg<true><<<N_NODES * 16 / 256, 256, 0, stream>>>(packed, offs, edge_w,
                                                        m16, agg, stats, bn_g, bn_b, h);
    k_mlp<<<NBMLP, 256, 0, stream>>>(h, w1tp + HPAD * 32, b1p + HPAD,
                                     w2p + HPAD * 32, conv_b2 + 32, pstat);
    k_statsR<<<64, 256, 0, stream>>>(pstat, stats + 64);
    k_poolhead<<<N_GRAPHS / 4, 256, 0, stream>>>(h, goff, stats + 64, bn_g + 32, bn_b + 32,
                                                 lin1_w, lin1_b, lin2_w, lin2_b, out);
}